// Round 18
// baseline (716.454 us; speedup 1.0000x reference)
//
#include <hip/hip_runtime.h>
#include <hip/hip_bf16.h>
#include <stdint.h>

using u16 = unsigned short;
using u32 = unsigned int;

typedef __attribute__((ext_vector_type(8))) __bf16 bf16x8;
typedef __attribute__((ext_vector_type(4))) float f32x4;

// ---------- helpers ----------
__device__ __forceinline__ float bf2f(u16 h) {
  u32 u = ((u32)h) << 16;
  return __builtin_bit_cast(float, u);
}
__device__ __forceinline__ u16 f2bf(float f) {
  u32 u = __builtin_bit_cast(u32, f);
  u += 0x7fffu + ((u >> 16) & 1u);   // RNE
  return (u16)(u >> 16);
}
__device__ __forceinline__ float blo(u32 u) { return __builtin_bit_cast(float, u << 16); }
__device__ __forceinline__ float bhi(u32 u) { return __builtin_bit_cast(float, u & 0xffff0000u); }

__device__ __forceinline__ uint4 cvt8(const float* s) {
  float4 f0 = *(const float4*)s;
  float4 f1 = *(const float4*)(s + 4);
  uint4 r;
  r.x = (u32)f2bf(f0.x) | ((u32)f2bf(f0.y) << 16);
  r.y = (u32)f2bf(f0.z) | ((u32)f2bf(f0.w) << 16);
  r.z = (u32)f2bf(f1.x) | ((u32)f2bf(f1.y) << 16);
  r.w = (u32)f2bf(f1.z) | ((u32)f2bf(f1.w) << 16);
  return r;
}

// tanh of packed bf16 differences
__device__ __forceinline__ u32 tanh2(u32 a, u32 b) {
  const float d0 = blo(a) - blo(b);
  const float d1 = bhi(a) - bhi(b);
  const float e0 = __expf(2.f * d0), e1 = __expf(2.f * d1);
  const float t0 = 1.f - 2.f * __builtin_amdgcn_rcpf(e0 + 1.f);
  const float t1 = 1.f - 2.f * __builtin_amdgcn_rcpf(e1 + 1.f);
  return (u32)f2bf(t0) | ((u32)f2bf(t1) << 16);
}

__device__ __forceinline__ void gl_lds(const u16* gsrc, u16* ldsbase) {
  __builtin_amdgcn_global_load_lds(
      (const __attribute__((address_space(1))) u32*)gsrc,
      (__attribute__((address_space(3))) u32*)ldsbase, 16, 0, 0);
}

// ---------- ws layout (bytes) ----------
//  params @ 0 (8864 u16 = 17728, pad 32768) | wT @ 32768 (1,179,648)
//  woT @ 1,212,416 (131,072) | wqfT @ 1,343,488 (32,768)  -> fixed = 1,376,256
//  x_bf @ fixed (52,428,800) | chunk after: qkv CB*38400, qf CB*3200
// params (u16): LN 0(1536) REL 1536(392) GBC 1928(5000 = rel+alpha*gbias+bqp)
//  ALPHA 6928(8) WQP 6936(512) BQP 7448(8) BQF 7456(64) BO 7520(256)
//  WQPT16 7776(1024 = [16 cols][64 k], cols 8-15 zero) ZPAD 8800(64 zeros)

// ---------- prep ----------
__global__ __launch_bounds__(256) void prep_kernel(
    const float* __restrict__ wq, const float* __restrict__ wk, const float* __restrict__ wv,
    const float* __restrict__ wo, const float* __restrict__ wqf,
    const float* __restrict__ lnqg, const float* __restrict__ lnqb,
    const float* __restrict__ lnkg, const float* __restrict__ lnkb,
    const float* __restrict__ lnvg, const float* __restrict__ lnvb,
    const float* __restrict__ relt, const float* __restrict__ gbias,
    const float* __restrict__ alphap,
    const float* __restrict__ wqp, const float* __restrict__ bqp,
    const float* __restrict__ bqf, const float* __restrict__ bo,
    u16* __restrict__ wT, u16* __restrict__ woT,
    u16* __restrict__ wqfT, u16* __restrict__ params)
{
  long long j = (long long)blockIdx.x * 256 + threadIdx.x;
  if (j < 589824) {                 // wT[col][k] = w_p[o][i][t], k=t*256+i
    int col = (int)(j / 768), k = (int)(j % 768);
    int p = col >> 8, o = col & 255, t = k >> 8, i = k & 255;
    const float* w = (p == 0) ? wq : (p == 1) ? wk : wv;
    wT[j] = f2bf(w[o * 768 + i * 3 + t]);
    return;
  }
  j -= 589824;
  if (j < 65536) {                  // woT[n][k] = wo[k][n]
    int n = (int)(j >> 8), k = (int)(j & 255);
    woT[j] = f2bf(wo[k * 256 + n]);
    return;
  }
  j -= 65536;
  if (j < 16384) {                  // wqfT[col][k] = wqf[k][col]
    int col = (int)(j >> 8), k = (int)(j & 255);
    wqfT[j] = f2bf(wqf[k * 64 + col]);
    return;
  }
  j -= 16384;
  if (j < 8864) {
    int t = (int)j;
    if (t >= 8800) { params[t] = 0; return; }               // zpad
    if (t >= 7776) {                                        // wqpT16[col][k]
      int t2 = t - 7776;
      int col = t2 >> 6, k = t2 & 63;
      params[t] = (col < 8) ? f2bf(wqp[k * 8 + col]) : (u16)0;
      return;
    }
    if (t >= 1928 && t < 6928) {    // combined bias: rel + alpha*gbias + bqp
      int idx = t - 1928;
      int h = idx / 625, rem = idx % 625, n = rem / 25, m = rem % 25;
      params[t] = f2bf(gbias[idx] * alphap[0] + relt[(n - m + 24) * 8 + h] + bqp[h]);
      return;
    }
    const float* src; int si;
    if (t < 1536) {
      int a = t >> 8, c = t & 255;
      src = (a == 0) ? lnqg : (a == 1) ? lnqb : (a == 2) ? lnkg
          : (a == 3) ? lnkb : (a == 4) ? lnvg : lnvb;
      si = c;
    } else if (t < 1928) { src = relt;  si = t - 1536; }
    else if (t < 6936)   { src = alphap; si = 0; }
    else if (t < 7448)   { src = wqp;   si = t - 6936; }
    else if (t < 7456)   { src = bqp;   si = t - 7448; }
    else if (t < 7520)   { src = bqf;   si = t - 7456; }
    else                 { src = bo;    si = t - 7520; }
    params[t] = f2bf(src[si]);
  }
}

// ---------- xconv: x (f32) -> x_bf ----------
__global__ __launch_bounds__(256) void xconv_kernel(
    const float* __restrict__ x, u16* __restrict__ xbf)
{
  const long long i = ((long long)blockIdx.x * 256 + threadIdx.x) * 8;
  *(uint4*)&xbf[i] = cvt8(x + i);
}

// ---------- convln: conv GEMM (BM=64 x BN=256) + fused LN + residual + qf tail ----------
// 1-D grid (rows/64 blocks), 256 threads = 4 waves; wave w owns 64 rows x cols [w*64..].
// p-loop inside block: all 3 projections share the SAME im2col A-tile -> A re-stages hit
// this CU's L1/L2 for p>=1 (same XCD). qf GEMM fused as a 4-K-step tail (A at tap t=1).
// XOR-swizzled LDS (pre-swizzled global source, unswizzled reads). 48 KB -> 3 blocks/CU.
__global__ __launch_bounds__(256) void convln_kernel(
    const u16* __restrict__ xbf, long long row0,
    const u16* __restrict__ wT, const u16* __restrict__ wqfT,
    u16* __restrict__ C,                 // chunk-local qkv [rows][768]
    u16* __restrict__ qfc,               // chunk-local qf [rows][64]
    const u16* __restrict__ params,
    const u16* __restrict__ zpad)
{
  __shared__ __align__(16) u16 Asm[64 * 64];
  __shared__ __align__(16) u16 Bsm[256 * 64];
  __shared__ float sG3[768];
  __shared__ float sB3[768];
  __shared__ float sSum[4][64];
  __shared__ float sSq[4][64];

  const int tid = threadIdx.x;
  const int l = tid & 63, w = tid >> 6;
  const int r0 = blockIdx.x * 64;
  const int lrow = l >> 3, chunk = l & 7;
  const int l15 = l & 15;
  const int rbase = 4 * (l >> 4);
  const int swz = l15 & 7;                // read-side chunk XOR (== row&7 for frag rows)

  for (int i = tid; i < 768; i += 256) {
    const int pp = i >> 8, cc = i & 255;
    sG3[i] = bf2f(params[pp * 512 + cc]);
    sB3[i] = bf2f(params[pp * 512 + 256 + cc]);
  }

  for (int p = 0; p < 3; ++p) {
    const int c0 = p * 256;

    f32x4 acc[4][4];
#pragma unroll
    for (int m = 0; m < 4; ++m)
#pragma unroll
      for (int n = 0; n < 4; ++n)
        acc[m][n] = (f32x4){0.f, 0.f, 0.f, 0.f};

    for (int ks = 0; ks < 12; ++ks) {
      const int k0 = ks * 64;
      const int t = k0 >> 8, kc = k0 & 255;
      __syncthreads();
      // stage A (64x64): 8 segs, 2/wave; p>=1 re-reads hit L1/L2 (same addresses)
#pragma unroll
      for (int it = 0; it < 2; ++it) {
        const int seg = w * 2 + it;
        const int row_l = seg * 8 + lrow;
        const bool valid = ((unsigned)((r0 + row_l) % 25 + t - 1) < 25u);
        const u16* src = valid
            ? xbf + (size_t)(row0 + r0 + row_l + t - 1) * 256 + kc + ((chunk ^ lrow) << 3)
            : zpad;
        gl_lds(src, &Asm[seg * 512]);
      }
      // stage B (256x64): 32 segs, 8/wave
#pragma unroll
      for (int it = 0; it < 8; ++it) {
        const int seg = w * 8 + it;
        const int row_l = seg * 8 + lrow;
        const u16* src = wT + (size_t)(c0 + row_l) * 768 + k0 + ((chunk ^ lrow) << 3);
        gl_lds(src, &Bsm[seg * 512]);
      }
      __syncthreads();

#pragma unroll
      for (int kk = 0; kk < 64; kk += 32) {
        const int c = (kk >> 3) + (l >> 4);
        const int co = ((c ^ swz) << 3);
        bf16x8 av[4], bv[4];
#pragma unroll
        for (int m = 0; m < 4; ++m)
          av[m] = *(const bf16x8*)&Asm[(m * 16 + l15) * 64 + co];
#pragma unroll
        for (int n = 0; n < 4; ++n)
          bv[n] = *(const bf16x8*)&Bsm[(w * 64 + n * 16 + l15) * 64 + co];
#pragma unroll
        for (int m = 0; m < 4; ++m)
#pragma unroll
          for (int n = 0; n < 4; ++n)
            acc[m][n] = __builtin_amdgcn_mfma_f32_16x16x32_bf16(av[m], bv[n], acc[m][n], 0, 0, 0);
      }
    }

    // ---- LN stats: per-thread partials -> 4 shuffles -> cross-wave LDS combine
#pragma unroll
    for (int m = 0; m < 4; ++m) {
#pragma unroll
      for (int r = 0; r < 4; ++r) {
        float s = 0.f, q = 0.f;
#pragma unroll
        for (int n = 0; n < 4; ++n) { const float v = acc[m][n][r]; s += v; q += v * v; }
#pragma unroll
        for (int mk = 1; mk < 16; mk <<= 1) {
          s += __shfl_xor(s, mk, 64);
          q += __shfl_xor(q, mk, 64);
        }
        if (l15 == 0) {
          const int row = m * 16 + rbase + r;
          sSum[w][row] = s;
          sSq[w][row] = q;
        }
      }
    }
    __syncthreads();

    // ---- normalize + gamma/beta + residual, store
#pragma unroll
    for (int m = 0; m < 4; ++m) {
      float mu4[4], rs4[4];
#pragma unroll
      for (int r = 0; r < 4; ++r) {
        const int row = m * 16 + rbase + r;
        const float tot = sSum[0][row] + sSum[1][row] + sSum[2][row] + sSum[3][row];
        const float tq  = sSq[0][row] + sSq[1][row] + sSq[2][row] + sSq[3][row];
        const float mu = tot * (1.f / 256.f);
        const float var = tq * (1.f / 256.f) - mu * mu;
        mu4[r] = mu;
        rs4[r] = rsqrtf(var + 1e-5f);
      }
#pragma unroll
      for (int n = 0; n < 4; ++n) {
        const int lc = w * 64 + n * 16 + l15;
        const float g = sG3[p * 256 + lc], bb = sB3[p * 256 + lc];
#pragma unroll
        for (int r = 0; r < 4; ++r) {
          const int row = m * 16 + rbase + r;
          const float xv = bf2f(xbf[(size_t)(row0 + r0 + row) * 256 + lc]);
          const float v = (acc[m][n][r] - mu4[r]) * rs4[r] * g + bb + xv;
          C[(size_t)(r0 + row) * 768 + c0 + lc] = f2bf(v);
        }
      }
    }
    __syncthreads();   // protect sSum/sSq reuse next p
  }

  // ---- qf tail: [64 x 64] = x @ wqfT^T (tap t=1, always valid); wave w owns 16 rows
  {
    f32x4 acc2[4];
#pragma unroll
    for (int n = 0; n < 4; ++n) acc2[n] = (f32x4){0.f, 0.f, 0.f, 0.f};

    for (int ki = 0; ki < 4; ++ki) {
      __syncthreads();
      // stage A (64x64): plain x rows, 8 segs, 2/wave (L2-hot from p-loop)
#pragma unroll
      for (int it = 0; it < 2; ++it) {
        const int seg = w * 2 + it;
        const int row_l = seg * 8 + lrow;
        const u16* src = xbf + (size_t)(row0 + r0 + row_l) * 256 + ki * 64
                       + ((chunk ^ lrow) << 3);
        gl_lds(src, &Asm[seg * 512]);
      }
      // stage B (64x64): 8 segs, 2/wave
#pragma unroll
      for (int it = 0; it < 2; ++it) {
        const int seg = w * 2 + it;
        const int row_l = seg * 8 + lrow;
        const u16* src = wqfT + (size_t)row_l * 256 + ki * 64 + ((chunk ^ lrow) << 3);
        gl_lds(src, &Bsm[seg * 512]);
      }
      __syncthreads();

#pragma unroll
      for (int kk = 0; kk < 64; kk += 32) {
        const int c = (kk >> 3) + (l >> 4);
        const int co = ((c ^ swz) << 3);
        const bf16x8 av = *(const bf16x8*)&Asm[(w * 16 + l15) * 64 + co];
#pragma unroll
        for (int n = 0; n < 4; ++n) {
          const bf16x8 bv = *(const bf16x8*)&Bsm[(n * 16 + l15) * 64 + co];
          acc2[n] = __builtin_amdgcn_mfma_f32_16x16x32_bf16(av, bv, acc2[n], 0, 0, 0);
        }
      }
    }
#pragma unroll
    for (int n = 0; n < 4; ++n) {
      const int col = n * 16 + l15;
      const float badd = bf2f(params[7456 + col]);
#pragma unroll
      for (int r = 0; r < 4; ++r) {
        const int row = r0 + w * 16 + rbase + r;
        qfc[(size_t)row * 64 + col] = f2bf(acc2[n][r] + badd);
      }
    }
  }
}

// ---------- MFMA GEMM (bf16 A, global_load_lds, XOR-swizzled): tiles 128 x BN ----------
template<int BN, bool HAS_BIAS, bool F32OUT>
__global__ __launch_bounds__(256) void gemm_kernel(
    const u16* __restrict__ A, int lda, long long row0,
    const u16* __restrict__ BT, int ldb,
    void* __restrict__ Cv, int ldc,
    const u16* __restrict__ bias,
    int ksteps)
{
  constexpr int NB = BN / 32;
  __shared__ __align__(16) u16 Asm[128 * 64];
  __shared__ __align__(16) u16 Bsm[BN * 64];

  const int tid = threadIdx.x;
  const int l = tid & 63;
  const int w = tid >> 6;
  const int c0 = blockIdx.x * BN;
  const int r0 = blockIdx.y * 128;
  const int wr = w >> 1, wc = w & 1;

  f32x4 acc[4][NB];
#pragma unroll
  for (int m = 0; m < 4; ++m)
#pragma unroll
    for (int n = 0; n < NB; ++n)
      acc[m][n] = (f32x4){0.f, 0.f, 0.f, 0.f};

  const int lrow = l >> 3;
  const int chunk = l & 7;
  const int l15 = l & 15;
  const int swz = l15 & 7;

  for (int ks = 0; ks < ksteps; ++ks) {
    const int k0 = ks * 64;
    __syncthreads();
#pragma unroll
    for (int it = 0; it < 4; ++it) {
      const int seg = w * 4 + it;
      const int row_l = seg * 8 + lrow;
      const u16* src = A + (size_t)(row0 + r0 + row_l) * lda + k0 + ((chunk ^ lrow) << 3);
      gl_lds(src, &Asm[seg * 512]);
    }
#pragma unroll
    for (int it = 0; it < NB; ++it) {
      const int seg = w * NB + it;
      const int row_l = seg * 8 + lrow;
      const u16* src = BT + (size_t)(c0 + row_l) * ldb + k0 + ((chunk ^ lrow) << 3);
      gl_lds(src, &Bsm[seg * 512]);
    }
    __syncthreads();

#pragma unroll
    for (int kk = 0; kk < 64; kk += 32) {
      const int c = (kk >> 3) + (l >> 4);
      const int co = ((c ^ swz) << 3);
      bf16x8 av[4], bv[NB];
#pragma unroll
      for (int m = 0; m < 4; ++m)
        av[m] = *(const bf16x8*)&Asm[(wr * 64 + m * 16 + l15) * 64 + co];
#pragma unroll
      for (int n = 0; n < NB; ++n)
        bv[n] = *(const bf16x8*)&Bsm[(wc * (BN / 2) + n * 16 + l15) * 64 + co];
#pragma unroll
      for (int m = 0; m < 4; ++m)
#pragma unroll
        for (int n = 0; n < NB; ++n)
          acc[m][n] = __builtin_amdgcn_mfma_f32_16x16x32_bf16(av[m], bv[n], acc[m][n], 0, 0, 0);
    }
  }

  const int rbase = 4 * (l >> 4);
#pragma unroll
  for (int m = 0; m < 4; ++m) {
#pragma unroll
    for (int n = 0; n < NB; ++n) {
      const int col = c0 + wc * (BN / 2) + n * 16 + l15;
      float badd = 0.f;
      if (HAS_BIAS) badd = bf2f(bias[col]);
#pragma unroll
      for (int r = 0; r < 4; ++r) {
        const int row = r0 + wr * 64 + m * 16 + rbase + r;
        const float v = acc[m][n][r] + badd;
        if constexpr (F32OUT) ((float*)Cv)[(size_t)row * ldc + col] = v;
        else                  ((u16*)Cv)[(size_t)row * ldc + col] = f2bf(v);
      }
    }
  }
}

// ---------- fused attention per batch (LN already applied to qkv) ----------
// LDS 38,848 B -> 4 blocks/CU, 4 barriers
__global__ __launch_bounds__(256) void attn_kernel(
    u16* __restrict__ qkv,                  // chunk-local [CB*25][768]; cols 0-255 get attn_out
    const u16* __restrict__ qf,             // chunk-local [CB*25][64]
    const u16* __restrict__ params)
{
  __shared__ __align__(16) char arena[38848];
  float* sS    = (float*)arena;
  u16*   sV    = (u16*)(arena + 20000);
  u16*   sQF   = (u16*)(arena + 33200);
  u16*   sWQPT = (u16*)(arena + 36800);

  const int b = blockIdx.x;
  const int tid = threadIdx.x;
  const int w = tid >> 6, l = tid & 63;
  const int g8 = (l >> 4) * 8;
  const int rbase = 4 * (l >> 4);
  const int l15 = l & 15;

  // ---- P0: stage V (LN'd), qf, wqpT
  {
    for (int i = tid; i < 800; i += 256) {
      const int m = i >> 5, c8 = (i & 31) * 8;
      *(uint4*)&sV[m * 264 + c8] =
          *(const uint4*)(qkv + (size_t)(b * 25 + m) * 768 + 512 + c8);
    }
    for (int i = tid; i < 200; i += 256) {
      const int r = i >> 3, c8 = (i & 7) * 8;
      *(uint4*)&sQF[r * 72 + c8] = *(const uint4*)(qf + (size_t)b * 1600 + r * 64 + c8);
    }
    for (int i = tid; i < 128; i += 256)
      ((uint4*)sWQPT)[i] = ((const uint4*)(params + 7776))[i];
  }
  __syncthreads();

  // ---- P1: dyn-bias tiles in registers + scores via MFMA (Q/K direct from global)
  f32x4 dt[10];
  {
    const bf16x8 bv0 = *(const bf16x8*)&sWQPT[l15 * 64 + g8];
    const bf16x8 bv1 = *(const bf16x8*)&sWQPT[l15 * 64 + 32 + g8];
#pragma unroll
    for (int ti = 0; ti < 10; ++ti) {
      const int p0 = (ti * 4 + w) * 16;
      int p = p0 + l15; if (p > 624) p = 624;
      const int n = p / 25, m = p % 25;
      const uint4 qn0 = *(const uint4*)&sQF[n * 72 + g8];
      const uint4 qn1 = *(const uint4*)&sQF[n * 72 + 32 + g8];
      const uint4 qm0 = *(const uint4*)&sQF[m * 72 + g8];
      const uint4 qm1 = *(const uint4*)&sQF[m * 72 + 32 + g8];
      u32 a0[4], a1[4];
      a0[0] = tanh2(qn0.x, qm0.x); a0[1] = tanh2(qn0.y, qm0.y);
      a0[2] = tanh2(qn0.z, qm0.z); a0[3] = tanh2(qn0.w, qm0.w);
      a1[0] = tanh2(qn1.x, qm1.x); a1[1] = tanh2(qn1.y, qm1.y);
      a1[2] = tanh2(qn1.z, qm1.z); a1[3] = tanh2(qn1.w, qm1.w);
      const bf16x8 av0 = __builtin_bit_cast(bf16x8, *(uint4*)a0);
      const bf16x8 av1 = __builtin_bit_cast(bf16x8, *(uint4*)a1);
      f32x4 d = (f32x4){0.f, 0.f, 0.f, 0.f};
      d = __builtin_amdgcn_mfma_f32_16x16x32_bf16(av0, bv0, d, 0, 0, 0);
      d = __builtin_amdgcn_mfma_f32_16x16x32_bf16(av1, bv1, d, 0, 0, 0);
      dt[ti] = d;
    }
    // scores: 2 heads/wave; fragments straight from global (16 rows x 64B pattern)
    bf16x8 zf8;
#pragma unroll
    for (int j = 0; j < 8; ++j) zf8[j] = (__bf16)0.f;
#pragma unroll
    for (int hh = 0; hh < 2; ++hh) {
      const int h = 2 * w + hh;
      bf16x8 qa[2], kb[2];
#pragma unroll
      for (int t = 0; t < 2; ++t) {
        const int row = l15 + 16 * t;
        if (row < 25) {
          const u16* base = qkv + (size_t)(b * 25 + row) * 768 + h * 32 + g8;
          qa[t] = *(const bf16x8*)base;
          kb[t] = *(const bf16x8*)(base + 256);
        } else { qa[t] = zf8; kb[t] = zf8; }
      }
#pragma unroll
      for (int tn = 0; tn < 2; ++tn)
#pragma unroll
        for (int tm = 0; tm < 2; ++tm) {
          f32x4 d = __builtin_amdgcn_mfma_f32_16x16x32_bf16(
              qa[tn], kb[tm], (f32x4){0.f, 0.f, 0.f, 0.f}, 0, 0, 0);
          const int m = l15 + 16 * tm;
#pragma unroll
          for (int r = 0; r < 4; ++r) {
            const int n = rbase + r + 16 * tn;
            if (n < 25 && m < 25) {
              const int idx = h * 625 + n * 25 + m;
              sS[idx] = d[r] * 0.17677669529663687f + bf2f(params[1928 + idx]);
            }
          }
        }
    }
  }
  __syncthreads();

  // ---- P2: scatter-add dyn tiles into sS
  {
    if (l15 < 8) {
      const int h = l15;
#pragma unroll
      for (int ti = 0; ti < 10; ++ti) {
        const int p0 = (ti * 4 + w) * 16;
#pragma unroll
        for (int r = 0; r < 4; ++r) {
          const int p = p0 + rbase + r;
          if (p < 625) sS[h * 625 + p] += dt[ti][r];
        }
      }
    }
  }
  __syncthreads();

  // ---- P3: softmax over m
  {
    for (int u = tid; u < 200; u += 256) {
      const int h = u / 25, n = u % 25;
      float* rp = &sS[h * 625 + n * 25];
      float mx = -1e30f;
#pragma unroll
      for (int m = 0; m < 25; ++m) mx = fmaxf(mx, rp[m]);
      float ssum = 0.f;
#pragma unroll
      for (int m = 0; m < 25; ++m) { rp[m] = __expf(rp[m] - mx); ssum += rp[m]; }
      const float inv = __builtin_amdgcn_rcpf(ssum);
#pragma unroll
      for (int m = 0; m < 25; ++m) rp[m] *= inv;
    }
  }
  __syncthreads();

  // ---- P4: PV via MFMA -> global qkv cols 0-255
  {
#pragma unroll
    for (int hh = 0; hh < 2; ++hh) {
      const int h = 2 * w + hh;
      bf16x8 pa[2], vb[2];
#pragma unroll
      for (int t = 0; t < 2; ++t) {
        const int n = l15 + 16 * t;
#pragma unroll
        for (int j = 0; j < 8; ++j) {
          const int m = g8 + j;
          const float pv = (n < 25 && m < 25) ? sS[h * 625 + n * 25 + m] : 0.f;
          pa[t][j] = (__bf16)pv;
        }
      }
#pragma unroll
      for (int t = 0; t < 2; ++t) {
        const int dcol = l15 + 16 * t;
#pragma unroll
        for (int j = 0; j < 8; ++j) {
          const int m = g8 + j;
          vb[t][j] = (m < 25)
              ? __builtin_bit_cast(__bf16, sV[m * 264 + h * 32 + dcol])
              : (__bf16)0.f;
        }
      }
#pragma unroll
      for (int tn = 0; tn < 2; ++tn)
#pragma unroll
        for (int td = 0; td < 2; ++td) {
          f32x4 d = __builtin_amdgcn_mfma_f32_16x16x32_bf16(
              pa[tn], vb[td], (f32x4){0.f, 0.f, 0.f, 0.f}, 0, 0, 0);
          const int dcol = l15 + 16 * td;
#pragma unroll
          for (int r = 0; r < 4; ++r) {
            const int n = rbase + r + 16 * tn;
            if (n < 25)
              qkv[(size_t)(b * 25 + n) * 768 + h * 32 + dcol] = f2bf(d[r]);
          }
        }
    }
  }
}

// ---------- launch ----------
extern "C" void kernel_launch(void* const* d_in, const int* in_sizes, int n_in,
                              void* d_out, int out_size, void* d_ws, size_t ws_size,
                              hipStream_t stream) {
  (void)in_sizes; (void)n_in; (void)out_size;
  const float* x    = (const float*)d_in[0];
  const float* wq   = (const float*)d_in[1];
  const float* wk   = (const float*)d_in[2];
  const float* wv   = (const float*)d_in[3];
  const float* lnqg = (const float*)d_in[4];
  const float* lnqb = (const float*)d_in[5];
  const float* lnkg = (const float*)d_in[6];
  const float* lnkb = (const float*)d_in[7];
  const float* lnvg = (const float*)d_in[8];
  const float* lnvb = (const float*)d_in[9];
  const float* relt = (const float*)d_in[10];
  const float* gbias= (const float*)d_in[11];
  const float* alph = (const float*)d_in[12];
  const float* wqf  = (const float*)d_in[13];
  const float* bqf  = (const float*)d_in[14];
  const float* wqp  = (const float*)d_in[15];
  const float* bqp  = (const float*)d_in[16];
  const float* wo   = (const float*)d_in[17];
  const float* bo   = (const float*)d_in[18];

  char* ws = (char*)d_ws;
  u16* params = (u16*)(ws + 0);
  u16* wT     = (u16*)(ws + 32768);
  u16* woT    = (u16*)(ws + 1212416);
  u16* wqfT   = (u16*)(ws + 1343488);
  const size_t fixed_bytes = 1376256;
  const size_t xbf_bytes = 52428800;
  const size_t per_batch = 41600;   // qkv 38400 + qf 3200 bytes
  u16* zpad = params + 8800;

  int CB = 4096;
  while (CB > 128 && fixed_bytes + xbf_bytes + (size_t)CB * per_batch > ws_size) CB >>= 1;
  const int nchunks = 4096 / CB;
  const int rows = CB * 25;

  u16* x_bf = (u16*)(ws + fixed_bytes);
  const size_t chunk_off = fixed_bytes + xbf_bytes;
  u16* qkv_c = (u16*)(ws + chunk_off);
  u16* qf_c  = (u16*)(ws + chunk_off + (size_t)CB * 38400);
  float* outf = (float*)d_out;

  prep_kernel<<<2659, 256, 0, stream>>>(
      wq, wk, wv, wo, wqf, lnqg, lnqb, lnkg, lnkb, lnvg, lnvb,
      relt, gbias, alph, wqp, bqp, bqf, bo,
      wT, woT, wqfT, params);
  xconv_kernel<<<12800, 256, 0, stream>>>(x, x_bf);

  for (int c = 0; c < nchunks; ++c) {
    const long long R0 = (long long)c * rows;

    // conv q/k/v projection + fused LN + residual + qf tail (p-loop inside block)
    convln_kernel<<<rows / 64, 256, 0, stream>>>(
        x_bf, R0, wT, wqfT, qkv_c, qf_c, params, zpad);

    // fused attention per batch
    attn_kernel<<<CB, 256, 0, stream>>>(qkv_c, qf_c, params);

    // output projection: [rows x 256] = attn_out @ wo + bo (f32 out)
    gemm_kernel<128, true, true><<<dim3(2, rows / 128), 256, 0, stream>>>(
        qkv_c, 768, 0, woT, 256, outf + (size_t)R0 * 256, 256, params + 7520, 4);
  }
}

// Round 19
// 382.641 us; speedup vs baseline: 1.8724x; 1.8724x over previous
//
#include <hip/hip_runtime.h>
#include <hip/hip_bf16.h>
#include <stdint.h>

using u16 = unsigned short;
using u32 = unsigned int;

typedef __attribute__((ext_vector_type(8))) __bf16 bf16x8;
typedef __attribute__((ext_vector_type(4))) float f32x4;

// ---------- helpers ----------
__device__ __forceinline__ float bf2f(u16 h) {
  u32 u = ((u32)h) << 16;
  return __builtin_bit_cast(float, u);
}
__device__ __forceinline__ u16 f2bf(float f) {
  u32 u = __builtin_bit_cast(u32, f);
  u += 0x7fffu + ((u >> 16) & 1u);   // RNE
  return (u16)(u >> 16);
}
__device__ __forceinline__ float blo(u32 u) { return __builtin_bit_cast(float, u << 16); }
__device__ __forceinline__ float bhi(u32 u) { return __builtin_bit_cast(float, u & 0xffff0000u); }

__device__ __forceinline__ uint4 cvt8(const float* s) {
  float4 f0 = *(const float4*)s;
  float4 f1 = *(const float4*)(s + 4);
  uint4 r;
  r.x = (u32)f2bf(f0.x) | ((u32)f2bf(f0.y) << 16);
  r.y = (u32)f2bf(f0.z) | ((u32)f2bf(f0.w) << 16);
  r.z = (u32)f2bf(f1.x) | ((u32)f2bf(f1.y) << 16);
  r.w = (u32)f2bf(f1.z) | ((u32)f2bf(f1.w) << 16);
  return r;
}

// tanh of packed bf16 differences
__device__ __forceinline__ u32 tanh2(u32 a, u32 b) {
  const float d0 = blo(a) - blo(b);
  const float d1 = bhi(a) - bhi(b);
  const float e0 = __expf(2.f * d0), e1 = __expf(2.f * d1);
  const float t0 = 1.f - 2.f * __builtin_amdgcn_rcpf(e0 + 1.f);
  const float t1 = 1.f - 2.f * __builtin_amdgcn_rcpf(e1 + 1.f);
  return (u32)f2bf(t0) | ((u32)f2bf(t1) << 16);
}

__device__ __forceinline__ void gl_lds(const u16* gsrc, u16* ldsbase) {
  __builtin_amdgcn_global_load_lds(
      (const __attribute__((address_space(1))) u32*)gsrc,
      (__attribute__((address_space(3))) u32*)ldsbase, 16, 0, 0);
}

// ---------- ws layout (bytes) ----------
//  params @ 0 (8864 u16 = 17728, pad 32768) | wT @ 32768 (1,179,648)
//  woT @ 1,212,416 (131,072) | wqfT @ 1,343,488 (32,768)  -> fixed = 1,376,256
//  x_bf @ fixed (52,428,800) | chunk after: qkv CB*38400, qf CB*3200
// params (u16): LN 0(1536) REL 1536(392) GBC 1928(5000 = rel+alpha*gbias+bqp)
//  ALPHA 6928(8) WQP 6936(512) BQP 7448(8) BQF 7456(64) BO 7520(256)
//  WQPT16 7776(1024 = [16 cols][64 k], cols 8-15 zero) ZPAD 8800(64 zeros)

// ---------- prep ----------
__global__ __launch_bounds__(256) void prep_kernel(
    const float* __restrict__ wq, const float* __restrict__ wk, const float* __restrict__ wv,
    const float* __restrict__ wo, const float* __restrict__ wqf,
    const float* __restrict__ lnqg, const float* __restrict__ lnqb,
    const float* __restrict__ lnkg, const float* __restrict__ lnkb,
    const float* __restrict__ lnvg, const float* __restrict__ lnvb,
    const float* __restrict__ relt, const float* __restrict__ gbias,
    const float* __restrict__ alphap,
    const float* __restrict__ wqp, const float* __restrict__ bqp,
    const float* __restrict__ bqf, const float* __restrict__ bo,
    u16* __restrict__ wT, u16* __restrict__ woT,
    u16* __restrict__ wqfT, u16* __restrict__ params)
{
  long long j = (long long)blockIdx.x * 256 + threadIdx.x;
  if (j < 589824) {                 // wT[col][k] = w_p[o][i][t], k=t*256+i
    int col = (int)(j / 768), k = (int)(j % 768);
    int p = col >> 8, o = col & 255, t = k >> 8, i = k & 255;
    const float* w = (p == 0) ? wq : (p == 1) ? wk : wv;
    wT[j] = f2bf(w[o * 768 + i * 3 + t]);
    return;
  }
  j -= 589824;
  if (j < 65536) {                  // woT[n][k] = wo[k][n]
    int n = (int)(j >> 8), k = (int)(j & 255);
    woT[j] = f2bf(wo[k * 256 + n]);
    return;
  }
  j -= 65536;
  if (j < 16384) {                  // wqfT[col][k] = wqf[k][col]
    int col = (int)(j >> 8), k = (int)(j & 255);
    wqfT[j] = f2bf(wqf[k * 64 + col]);
    return;
  }
  j -= 16384;
  if (j < 8864) {
    int t = (int)j;
    if (t >= 8800) { params[t] = 0; return; }               // zpad
    if (t >= 7776) {                                        // wqpT16[col][k]
      int t2 = t - 7776;
      int col = t2 >> 6, k = t2 & 63;
      params[t] = (col < 8) ? f2bf(wqp[k * 8 + col]) : (u16)0;
      return;
    }
    if (t >= 1928 && t < 6928) {    // combined bias: rel + alpha*gbias + bqp
      int idx = t - 1928;
      int h = idx / 625, rem = idx % 625, n = rem / 25, m = rem % 25;
      params[t] = f2bf(gbias[idx] * alphap[0] + relt[(n - m + 24) * 8 + h] + bqp[h]);
      return;
    }
    const float* src; int si;
    if (t < 1536) {
      int a = t >> 8, c = t & 255;
      src = (a == 0) ? lnqg : (a == 1) ? lnqb : (a == 2) ? lnkg
          : (a == 3) ? lnkb : (a == 4) ? lnvg : lnvb;
      si = c;
    } else if (t < 1928) { src = relt;  si = t - 1536; }
    else if (t < 6936)   { src = alphap; si = 0; }
    else if (t < 7448)   { src = wqp;   si = t - 6936; }
    else if (t < 7456)   { src = bqp;   si = t - 7448; }
    else if (t < 7520)   { src = bqf;   si = t - 7456; }
    else                 { src = bo;    si = t - 7520; }
    params[t] = f2bf(src[si]);
  }
}

// ---------- xconv: x (f32) -> x_bf ----------
__global__ __launch_bounds__(256) void xconv_kernel(
    const float* __restrict__ x, u16* __restrict__ xbf)
{
  const long long i = ((long long)blockIdx.x * 256 + threadIdx.x) * 8;
  *(uint4*)&xbf[i] = cvt8(x + i);
}

// ---------- convln: conv GEMM (BM=64 x BN=256) + fused LN + residual ----------
// 256 threads = 4 waves; wave w owns 64 rows x cols [w*64, w*64+64).
// XOR-swizzled LDS (pre-swizzled global source, unswizzled reads).
__global__ __launch_bounds__(256) void convln_kernel(
    const u16* __restrict__ xbf, long long row0,
    const u16* __restrict__ wT,
    u16* __restrict__ C,                 // chunk-local qkv [rows][768]
    const u16* __restrict__ params,
    const u16* __restrict__ zpad)
{
  __shared__ __align__(16) u16 Asm[64 * 64];
  __shared__ __align__(16) u16 Bsm[256 * 64];
  __shared__ float sG[256];
  __shared__ float sB[256];
  __shared__ float sSum[4][64];
  __shared__ float sSq[4][64];

  const int tid = threadIdx.x;
  const int l = tid & 63, w = tid >> 6;
  const int p = blockIdx.x;               // projection 0..2
  const int c0 = p * 256;
  const int r0 = blockIdx.y * 64;
  const int lrow = l >> 3, chunk = l & 7;
  const int g8 = (l >> 4) * 8, l15 = l & 15;
  const int rbase = 4 * (l >> 4);
  const int swz = l15 & 7;                // read-side chunk XOR (== row&7 for all frag rows)

  sG[tid] = bf2f(params[p * 512 + tid]);
  sB[tid] = bf2f(params[p * 512 + 256 + tid]);

  f32x4 acc[4][4];
#pragma unroll
  for (int m = 0; m < 4; ++m)
#pragma unroll
    for (int n = 0; n < 4; ++n)
      acc[m][n] = (f32x4){0.f, 0.f, 0.f, 0.f};

  for (int ks = 0; ks < 12; ++ks) {
    const int k0 = ks * 64;
    const int t = k0 >> 8, kc = k0 & 255;
    __syncthreads();
    // stage A (64x64): 8 segs, 2/wave; source pre-swizzled by chunk^lrow
#pragma unroll
    for (int it = 0; it < 2; ++it) {
      const int seg = w * 2 + it;
      const int row_l = seg * 8 + lrow;
      const bool valid = ((unsigned)((r0 + row_l) % 25 + t - 1) < 25u);
      const u16* src = valid
          ? xbf + (size_t)(row0 + r0 + row_l + t - 1) * 256 + kc + ((chunk ^ lrow) << 3)
          : zpad;
      gl_lds(src, &Asm[seg * 512]);
    }
    // stage B (256x64): 32 segs, 8/wave
#pragma unroll
    for (int it = 0; it < 8; ++it) {
      const int seg = w * 8 + it;
      const int row_l = seg * 8 + lrow;
      const u16* src = wT + (size_t)(c0 + row_l) * 768 + k0 + ((chunk ^ lrow) << 3);
      gl_lds(src, &Bsm[seg * 512]);
    }
    __syncthreads();

#pragma unroll
    for (int kk = 0; kk < 64; kk += 32) {
      const int c = (kk >> 3) + (l >> 4);
      const int co = ((c ^ swz) << 3);
      bf16x8 av[4], bv[4];
#pragma unroll
      for (int m = 0; m < 4; ++m)
        av[m] = *(const bf16x8*)&Asm[(m * 16 + l15) * 64 + co];
#pragma unroll
      for (int n = 0; n < 4; ++n)
        bv[n] = *(const bf16x8*)&Bsm[(w * 64 + n * 16 + l15) * 64 + co];
#pragma unroll
      for (int m = 0; m < 4; ++m)
#pragma unroll
        for (int n = 0; n < 4; ++n)
          acc[m][n] = __builtin_amdgcn_mfma_f32_16x16x32_bf16(av[m], bv[n], acc[m][n], 0, 0, 0);
    }
  }

  // ---- LN stats: per-thread partials -> 4 shuffles -> cross-wave LDS combine
#pragma unroll
  for (int m = 0; m < 4; ++m) {
#pragma unroll
    for (int r = 0; r < 4; ++r) {
      float s = 0.f, q = 0.f;
#pragma unroll
      for (int n = 0; n < 4; ++n) { const float v = acc[m][n][r]; s += v; q += v * v; }
#pragma unroll
      for (int mk = 1; mk < 16; mk <<= 1) {
        s += __shfl_xor(s, mk, 64);
        q += __shfl_xor(q, mk, 64);
      }
      if (l15 == 0) {
        const int row = m * 16 + rbase + r;
        sSum[w][row] = s;
        sSq[w][row] = q;
      }
    }
  }
  __syncthreads();

  // ---- normalize + gamma/beta + residual, store
#pragma unroll
  for (int m = 0; m < 4; ++m) {
    float mu4[4], rs4[4];
#pragma unroll
    for (int r = 0; r < 4; ++r) {
      const int row = m * 16 + rbase + r;
      const float tot = sSum[0][row] + sSum[1][row] + sSum[2][row] + sSum[3][row];
      const float tq  = sSq[0][row] + sSq[1][row] + sSq[2][row] + sSq[3][row];
      const float mu = tot * (1.f / 256.f);
      const float var = tq * (1.f / 256.f) - mu * mu;
      mu4[r] = mu;
      rs4[r] = rsqrtf(var + 1e-5f);
    }
#pragma unroll
    for (int n = 0; n < 4; ++n) {
      const int lc = w * 64 + n * 16 + l15;
      const float g = sG[lc], bb = sB[lc];
#pragma unroll
      for (int r = 0; r < 4; ++r) {
        const int row = m * 16 + rbase + r;
        const float xv = bf2f(xbf[(size_t)(row0 + r0 + row) * 256 + lc]);
        const float v = (acc[m][n][r] - mu4[r]) * rs4[r] * g + bb + xv;
        C[(size_t)(r0 + row) * 768 + c0 + lc] = f2bf(v);
      }
    }
  }
}

// ---------- MFMA GEMM (bf16 A, global_load_lds, XOR-swizzled): tiles 128 x BN ----------
template<int BN, bool HAS_BIAS, bool F32OUT>
__global__ __launch_bounds__(256) void gemm_kernel(
    const u16* __restrict__ A, int lda, long long row0,
    const u16* __restrict__ BT, int ldb,
    void* __restrict__ Cv, int ldc,
    const u16* __restrict__ bias,
    int ksteps)
{
  constexpr int NB = BN / 32;
  __shared__ __align__(16) u16 Asm[128 * 64];
  __shared__ __align__(16) u16 Bsm[BN * 64];

  const int tid = threadIdx.x;
  const int l = tid & 63;
  const int w = tid >> 6;
  const int c0 = blockIdx.x * BN;
  const int r0 = blockIdx.y * 128;
  const int wr = w >> 1, wc = w & 1;

  f32x4 acc[4][NB];
#pragma unroll
  for (int m = 0; m < 4; ++m)
#pragma unroll
    for (int n = 0; n < NB; ++n)
      acc[m][n] = (f32x4){0.f, 0.f, 0.f, 0.f};

  const int lrow = l >> 3;
  const int chunk = l & 7;
  const int l15 = l & 15;
  const int swz = l15 & 7;

  for (int ks = 0; ks < ksteps; ++ks) {
    const int k0 = ks * 64;
    __syncthreads();
#pragma unroll
    for (int it = 0; it < 4; ++it) {
      const int seg = w * 4 + it;
      const int row_l = seg * 8 + lrow;
      const u16* src = A + (size_t)(row0 + r0 + row_l) * lda + k0 + ((chunk ^ lrow) << 3);
      gl_lds(src, &Asm[seg * 512]);
    }
#pragma unroll
    for (int it = 0; it < NB; ++it) {
      const int seg = w * NB + it;
      const int row_l = seg * 8 + lrow;
      const u16* src = BT + (size_t)(c0 + row_l) * ldb + k0 + ((chunk ^ lrow) << 3);
      gl_lds(src, &Bsm[seg * 512]);
    }
    __syncthreads();

#pragma unroll
    for (int kk = 0; kk < 64; kk += 32) {
      const int c = (kk >> 3) + (l >> 4);
      const int co = ((c ^ swz) << 3);
      bf16x8 av[4], bv[NB];
#pragma unroll
      for (int m = 0; m < 4; ++m)
        av[m] = *(const bf16x8*)&Asm[(wr * 64 + m * 16 + l15) * 64 + co];
#pragma unroll
      for (int n = 0; n < NB; ++n)
        bv[n] = *(const bf16x8*)&Bsm[(wc * (BN / 2) + n * 16 + l15) * 64 + co];
#pragma unroll
      for (int m = 0; m < 4; ++m)
#pragma unroll
        for (int n = 0; n < NB; ++n)
          acc[m][n] = __builtin_amdgcn_mfma_f32_16x16x32_bf16(av[m], bv[n], acc[m][n], 0, 0, 0);
    }
  }

  const int rbase = 4 * (l >> 4);
#pragma unroll
  for (int m = 0; m < 4; ++m) {
#pragma unroll
    for (int n = 0; n < NB; ++n) {
      const int col = c0 + wc * (BN / 2) + n * 16 + l15;
      float badd = 0.f;
      if (HAS_BIAS) badd = bf2f(bias[col]);
#pragma unroll
      for (int r = 0; r < 4; ++r) {
        const int row = r0 + wr * 64 + m * 16 + rbase + r;
        const float v = acc[m][n][r] + badd;
        if constexpr (F32OUT) ((float*)Cv)[(size_t)row * ldc + col] = v;
        else                  ((u16*)Cv)[(size_t)row * ldc + col] = f2bf(v);
      }
    }
  }
}

// ---------- fused attention per batch (LN already applied to qkv) ----------
// LDS 38,848 B -> 4 blocks/CU, 4 barriers
__global__ __launch_bounds__(256) void attn_kernel(
    u16* __restrict__ qkv,                  // chunk-local [CB*25][768]; cols 0-255 get attn_out
    const u16* __restrict__ qf,             // chunk-local [CB*25][64]
    const u16* __restrict__ params)
{
  __shared__ __align__(16) char arena[38848];
  float* sS    = (float*)arena;
  u16*   sV    = (u16*)(arena + 20000);
  u16*   sQF   = (u16*)(arena + 33200);
  u16*   sWQPT = (u16*)(arena + 36800);

  const int b = blockIdx.x;
  const int tid = threadIdx.x;
  const int w = tid >> 6, l = tid & 63;
  const int g8 = (l >> 4) * 8;
  const int rbase = 4 * (l >> 4);
  const int l15 = l & 15;

  // ---- P0: stage V (LN'd), qf, wqpT
  {
    for (int i = tid; i < 800; i += 256) {
      const int m = i >> 5, c8 = (i & 31) * 8;
      *(uint4*)&sV[m * 264 + c8] =
          *(const uint4*)(qkv + (size_t)(b * 25 + m) * 768 + 512 + c8);
    }
    for (int i = tid; i < 200; i += 256) {
      const int r = i >> 3, c8 = (i & 7) * 8;
      *(uint4*)&sQF[r * 72 + c8] = *(const uint4*)(qf + (size_t)b * 1600 + r * 64 + c8);
    }
    for (int i = tid; i < 128; i += 256)
      ((uint4*)sWQPT)[i] = ((const uint4*)(params + 7776))[i];
  }
  __syncthreads();

  // ---- P1: dyn-bias tiles in registers + scores via MFMA (Q/K direct from global)
  f32x4 dt[10];
  {
    const bf16x8 bv0 = *(const bf16x8*)&sWQPT[l15 * 64 + g8];
    const bf16x8 bv1 = *(const bf16x8*)&sWQPT[l15 * 64 + 32 + g8];
#pragma unroll
    for (int ti = 0; ti < 10; ++ti) {
      const int p0 = (ti * 4 + w) * 16;
      int p = p0 + l15; if (p > 624) p = 624;
      const int n = p / 25, m = p % 25;
      const uint4 qn0 = *(const uint4*)&sQF[n * 72 + g8];
      const uint4 qn1 = *(const uint4*)&sQF[n * 72 + 32 + g8];
      const uint4 qm0 = *(const uint4*)&sQF[m * 72 + g8];
      const uint4 qm1 = *(const uint4*)&sQF[m * 72 + 32 + g8];
      u32 a0[4], a1[4];
      a0[0] = tanh2(qn0.x, qm0.x); a0[1] = tanh2(qn0.y, qm0.y);
      a0[2] = tanh2(qn0.z, qm0.z); a0[3] = tanh2(qn0.w, qm0.w);
      a1[0] = tanh2(qn1.x, qm1.x); a1[1] = tanh2(qn1.y, qm1.y);
      a1[2] = tanh2(qn1.z, qm1.z); a1[3] = tanh2(qn1.w, qm1.w);
      const bf16x8 av0 = __builtin_bit_cast(bf16x8, *(uint4*)a0);
      const bf16x8 av1 = __builtin_bit_cast(bf16x8, *(uint4*)a1);
      f32x4 d = (f32x4){0.f, 0.f, 0.f, 0.f};
      d = __builtin_amdgcn_mfma_f32_16x16x32_bf16(av0, bv0, d, 0, 0, 0);
      d = __builtin_amdgcn_mfma_f32_16x16x32_bf16(av1, bv1, d, 0, 0, 0);
      dt[ti] = d;
    }
    // scores: 2 heads/wave; fragments straight from global (16 rows x 64B pattern)
    bf16x8 zf8;
#pragma unroll
    for (int j = 0; j < 8; ++j) zf8[j] = (__bf16)0.f;
#pragma unroll
    for (int hh = 0; hh < 2; ++hh) {
      const int h = 2 * w + hh;
      bf16x8 qa[2], kb[2];
#pragma unroll
      for (int t = 0; t < 2; ++t) {
        const int row = l15 + 16 * t;
        if (row < 25) {
          const u16* base = qkv + (size_t)(b * 25 + row) * 768 + h * 32 + g8;
          qa[t] = *(const bf16x8*)base;
          kb[t] = *(const bf16x8*)(base + 256);
        } else { qa[t] = zf8; kb[t] = zf8; }
      }
#pragma unroll
      for (int tn = 0; tn < 2; ++tn)
#pragma unroll
        for (int tm = 0; tm < 2; ++tm) {
          f32x4 d = __builtin_amdgcn_mfma_f32_16x16x32_bf16(
              qa[tn], kb[tm], (f32x4){0.f, 0.f, 0.f, 0.f}, 0, 0, 0);
          const int m = l15 + 16 * tm;
#pragma unroll
          for (int r = 0; r < 4; ++r) {
            const int n = rbase + r + 16 * tn;
            if (n < 25 && m < 25) {
              const int idx = h * 625 + n * 25 + m;
              sS[idx] = d[r] * 0.17677669529663687f + bf2f(params[1928 + idx]);
            }
          }
        }
    }
  }
  __syncthreads();

  // ---- P2: scatter-add dyn tiles into sS
  {
    if (l15 < 8) {
      const int h = l15;
#pragma unroll
      for (int ti = 0; ti < 10; ++ti) {
        const int p0 = (ti * 4 + w) * 16;
#pragma unroll
        for (int r = 0; r < 4; ++r) {
          const int p = p0 + rbase + r;
          if (p < 625) sS[h * 625 + p] += dt[ti][r];
        }
      }
    }
  }
  __syncthreads();

  // ---- P3: softmax over m
  {
    for (int u = tid; u < 200; u += 256) {
      const int h = u / 25, n = u % 25;
      float* rp = &sS[h * 625 + n * 25];
      float mx = -1e30f;
#pragma unroll
      for (int m = 0; m < 25; ++m) mx = fmaxf(mx, rp[m]);
      float ssum = 0.f;
#pragma unroll
      for (int m = 0; m < 25; ++m) { rp[m] = __expf(rp[m] - mx); ssum += rp[m]; }
      const float inv = __builtin_amdgcn_rcpf(ssum);
#pragma unroll
      for (int m = 0; m < 25; ++m) rp[m] *= inv;
    }
  }
  __syncthreads();

  // ---- P4: PV via MFMA -> global qkv cols 0-255
  {
#pragma unroll
    for (int hh = 0; hh < 2; ++hh) {
      const int h = 2 * w + hh;
      bf16x8 pa[2], vb[2];
#pragma unroll
      for (int t = 0; t < 2; ++t) {
        const int n = l15 + 16 * t;
#pragma unroll
        for (int j = 0; j < 8; ++j) {
          const int m = g8 + j;
          const float pv = (n < 25 && m < 25) ? sS[h * 625 + n * 25 + m] : 0.f;
          pa[t][j] = (__bf16)pv;
        }
      }
#pragma unroll
      for (int t = 0; t < 2; ++t) {
        const int dcol = l15 + 16 * t;
#pragma unroll
        for (int j = 0; j < 8; ++j) {
          const int m = g8 + j;
          vb[t][j] = (m < 25)
              ? __builtin_bit_cast(__bf16, sV[m * 264 + h * 32 + dcol])
              : (__bf16)0.f;
        }
      }
#pragma unroll
      for (int tn = 0; tn < 2; ++tn)
#pragma unroll
        for (int td = 0; td < 2; ++td) {
          f32x4 d = __builtin_amdgcn_mfma_f32_16x16x32_bf16(
              pa[tn], vb[td], (f32x4){0.f, 0.f, 0.f, 0.f}, 0, 0, 0);
          const int dcol = l15 + 16 * td;
#pragma unroll
          for (int r = 0; r < 4; ++r) {
            const int n = rbase + r + 16 * tn;
            if (n < 25)
              qkv[(size_t)(b * 25 + n) * 768 + h * 32 + dcol] = f2bf(d[r]);
          }
        }
    }
  }
}

// ---------- launch ----------
extern "C" void kernel_launch(void* const* d_in, const int* in_sizes, int n_in,
                              void* d_out, int out_size, void* d_ws, size_t ws_size,
                              hipStream_t stream) {
  (void)in_sizes; (void)n_in; (void)out_size;
  const float* x    = (const float*)d_in[0];
  const float* wq   = (const float*)d_in[1];
  const float* wk   = (const float*)d_in[2];
  const float* wv   = (const float*)d_in[3];
  const float* lnqg = (const float*)d_in[4];
  const float* lnqb = (const float*)d_in[5];
  const float* lnkg = (const float*)d_in[6];
  const float* lnkb = (const float*)d_in[7];
  const float* lnvg = (const float*)d_in[8];
  const float* lnvb = (const float*)d_in[9];
  const float* relt = (const float*)d_in[10];
  const float* gbias= (const float*)d_in[11];
  const float* alph = (const float*)d_in[12];
  const float* wqf  = (const float*)d_in[13];
  const float* bqf  = (const float*)d_in[14];
  const float* wqp  = (const float*)d_in[15];
  const float* bqp  = (const float*)d_in[16];
  const float* wo   = (const float*)d_in[17];
  const float* bo   = (const float*)d_in[18];

  char* ws = (char*)d_ws;
  u16* params = (u16*)(ws + 0);
  u16* wT     = (u16*)(ws + 32768);
  u16* woT    = (u16*)(ws + 1212416);
  u16* wqfT   = (u16*)(ws + 1343488);
  const size_t fixed_bytes = 1376256;
  const size_t xbf_bytes = 52428800;
  const size_t per_batch = 41600;   // qkv 38400 + qf 3200 bytes
  u16* zpad = params + 8800;

  int CB = 4096;
  while (CB > 128 && fixed_bytes + xbf_bytes + (size_t)CB * per_batch > ws_size) CB >>= 1;
  const int nchunks = 4096 / CB;
  const int rows = CB * 25;

  u16* x_bf = (u16*)(ws + fixed_bytes);
  const size_t chunk_off = fixed_bytes + xbf_bytes;
  u16* qkv_c = (u16*)(ws + chunk_off);
  u16* qf_c  = (u16*)(ws + chunk_off + (size_t)CB * 38400);
  float* outf = (float*)d_out;

  prep_kernel<<<2659, 256, 0, stream>>>(
      wq, wk, wv, wo, wqf, lnqg, lnqb, lnkg, lnkb, lnvg, lnvb,
      relt, gbias, alph, wqp, bqp, bqf, bo,
      wT, woT, wqfT, params);
  xconv_kernel<<<12800, 256, 0, stream>>>(x, x_bf);

  for (int c = 0; c < nchunks; ++c) {
    const long long R0 = (long long)c * rows;

    // conv q/k/v projection + fused LN + residual (BM=64 tiles)
    convln_kernel<<<dim3(3, rows / 64), 256, 0, stream>>>(
        x_bf, R0, wT, qkv_c, params, zpad);

    // qf: [rows x 64] = x @ wqf + bqf
    gemm_kernel<64, true, false><<<dim3(1, rows / 128), 256, 0, stream>>>(
        x_bf, 256, R0, wqfT, 256, qf_c, 64, params + 7456, 4);

    // fused attention per batch
    attn_kernel<<<CB, 256, 0, stream>>>(qkv_c, qf_c, params);

    // output projection: [rows x 256] = attn_out @ wo + bo (f32 out)
    gemm_kernel<128, true, true><<<dim3(2, rows / 128), 256, 0, stream>>>(
        qkv_c, 768, 0, woT, 256, outf + (size_t)R0 * 256, 256, params + 7520, 4);
  }
}

// Round 20
// 375.804 us; speedup vs baseline: 1.9065x; 1.0182x over previous
//
#include <hip/hip_runtime.h>
#include <hip/hip_bf16.h>
#include <stdint.h>

using u16 = unsigned short;
using u32 = unsigned int;

typedef __attribute__((ext_vector_type(8))) __bf16 bf16x8;
typedef __attribute__((ext_vector_type(4))) float f32x4;

// ---------- helpers ----------
__device__ __forceinline__ float bf2f(u16 h) {
  u32 u = ((u32)h) << 16;
  return __builtin_bit_cast(float, u);
}
__device__ __forceinline__ u16 f2bf(float f) {
  u32 u = __builtin_bit_cast(u32, f);
  u += 0x7fffu + ((u >> 16) & 1u);   // RNE
  return (u16)(u >> 16);
}
__device__ __forceinline__ float blo(u32 u) { return __builtin_bit_cast(float, u << 16); }
__device__ __forceinline__ float bhi(u32 u) { return __builtin_bit_cast(float, u & 0xffff0000u); }

__device__ __forceinline__ uint4 cvt8(const float* s) {
  float4 f0 = *(const float4*)s;
  float4 f1 = *(const float4*)(s + 4);
  uint4 r;
  r.x = (u32)f2bf(f0.x) | ((u32)f2bf(f0.y) << 16);
  r.y = (u32)f2bf(f0.z) | ((u32)f2bf(f0.w) << 16);
  r.z = (u32)f2bf(f1.x) | ((u32)f2bf(f1.y) << 16);
  r.w = (u32)f2bf(f1.z) | ((u32)f2bf(f1.w) << 16);
  return r;
}

// tanh of packed bf16 differences
__device__ __forceinline__ u32 tanh2(u32 a, u32 b) {
  const float d0 = blo(a) - blo(b);
  const float d1 = bhi(a) - bhi(b);
  const float e0 = __expf(2.f * d0), e1 = __expf(2.f * d1);
  const float t0 = 1.f - 2.f * __builtin_amdgcn_rcpf(e0 + 1.f);
  const float t1 = 1.f - 2.f * __builtin_amdgcn_rcpf(e1 + 1.f);
  return (u32)f2bf(t0) | ((u32)f2bf(t1) << 16);
}

__device__ __forceinline__ void gl_lds(const u16* gsrc, u16* ldsbase) {
  __builtin_amdgcn_global_load_lds(
      (const __attribute__((address_space(1))) u32*)gsrc,
      (__attribute__((address_space(3))) u32*)ldsbase, 16, 0, 0);
}

// ---------- ws layout (bytes) ----------
//  params @ 0 (8864 u16 = 17728, pad 32768) | wT @ 32768 (1,179,648)
//  woT @ 1,212,416 (131,072) | wqfT @ 1,343,488 (32,768)  -> fixed = 1,376,256
//  x_bf @ fixed (52,428,800) | chunk after: qkv CB*38400, qf CB*3200
// params (u16): LN 0(1536) REL 1536(392) GBC 1928(5000 = rel+alpha*gbias+bqp)
//  ALPHA 6928(8) WQP 6936(512) BQP 7448(8) BQF 7456(64) BO 7520(256)
//  WQPT16 7776(1024 = [16 cols][64 k], cols 8-15 zero) ZPAD 8800(64 zeros)

// ---------- prep ----------
__global__ __launch_bounds__(256) void prep_kernel(
    const float* __restrict__ wq, const float* __restrict__ wk, const float* __restrict__ wv,
    const float* __restrict__ wo, const float* __restrict__ wqf,
    const float* __restrict__ lnqg, const float* __restrict__ lnqb,
    const float* __restrict__ lnkg, const float* __restrict__ lnkb,
    const float* __restrict__ lnvg, const float* __restrict__ lnvb,
    const float* __restrict__ relt, const float* __restrict__ gbias,
    const float* __restrict__ alphap,
    const float* __restrict__ wqp, const float* __restrict__ bqp,
    const float* __restrict__ bqf, const float* __restrict__ bo,
    u16* __restrict__ wT, u16* __restrict__ woT,
    u16* __restrict__ wqfT, u16* __restrict__ params)
{
  long long j = (long long)blockIdx.x * 256 + threadIdx.x;
  if (j < 589824) {                 // wT[col][k] = w_p[o][i][t], k=t*256+i
    int col = (int)(j / 768), k = (int)(j % 768);
    int p = col >> 8, o = col & 255, t = k >> 8, i = k & 255;
    const float* w = (p == 0) ? wq : (p == 1) ? wk : wv;
    wT[j] = f2bf(w[o * 768 + i * 3 + t]);
    return;
  }
  j -= 589824;
  if (j < 65536) {                  // woT[n][k] = wo[k][n]
    int n = (int)(j >> 8), k = (int)(j & 255);
    woT[j] = f2bf(wo[k * 256 + n]);
    return;
  }
  j -= 65536;
  if (j < 16384) {                  // wqfT[col][k] = wqf[k][col]
    int col = (int)(j >> 8), k = (int)(j & 255);
    wqfT[j] = f2bf(wqf[k * 64 + col]);
    return;
  }
  j -= 16384;
  if (j < 8864) {
    int t = (int)j;
    if (t >= 8800) { params[t] = 0; return; }               // zpad
    if (t >= 7776) {                                        // wqpT16[col][k]
      int t2 = t - 7776;
      int col = t2 >> 6, k = t2 & 63;
      params[t] = (col < 8) ? f2bf(wqp[k * 8 + col]) : (u16)0;
      return;
    }
    if (t >= 1928 && t < 6928) {    // combined bias: rel + alpha*gbias + bqp
      int idx = t - 1928;
      int h = idx / 625, rem = idx % 625, n = rem / 25, m = rem % 25;
      params[t] = f2bf(gbias[idx] * alphap[0] + relt[(n - m + 24) * 8 + h] + bqp[h]);
      return;
    }
    const float* src; int si;
    if (t < 1536) {
      int a = t >> 8, c = t & 255;
      src = (a == 0) ? lnqg : (a == 1) ? lnqb : (a == 2) ? lnkg
          : (a == 3) ? lnkb : (a == 4) ? lnvg : lnvb;
      si = c;
    } else if (t < 1928) { src = relt;  si = t - 1536; }
    else if (t < 6936)   { src = alphap; si = 0; }
    else if (t < 7448)   { src = wqp;   si = t - 6936; }
    else if (t < 7456)   { src = bqp;   si = t - 7448; }
    else if (t < 7520)   { src = bqf;   si = t - 7456; }
    else                 { src = bo;    si = t - 7520; }
    params[t] = f2bf(src[si]);
  }
}

// ---------- xconv: x (f32) -> x_bf ----------
__global__ __launch_bounds__(256) void xconv_kernel(
    const float* __restrict__ x, u16* __restrict__ xbf)
{
  const long long i = ((long long)blockIdx.x * 256 + threadIdx.x) * 8;
  *(uint4*)&xbf[i] = cvt8(x + i);
}

// ---------- convln: conv GEMM (BM=64 x BN=256) + fused LN + residual ----------
// 256 threads = 4 waves; wave w owns 64 rows x cols [w*64, w*64+64).
// XOR-swizzled LDS (pre-swizzled global source, unswizzled reads).
// 1-D grid (3*ny blocks) with XCD-aware decode: the 3 projections of the same
// y-tile get bids differing by 8 -> same XCD (bid%8) -> shared-A L2 hits.
__global__ __launch_bounds__(256) void convln_kernel(
    const u16* __restrict__ xbf, long long row0,
    const u16* __restrict__ wT,
    u16* __restrict__ C,                 // chunk-local qkv [rows][768]
    const u16* __restrict__ params,
    const u16* __restrict__ zpad)
{
  __shared__ __align__(16) u16 Asm[64 * 64];
  __shared__ __align__(16) u16 Bsm[256 * 64];
  __shared__ float sG[256];
  __shared__ float sB[256];
  __shared__ float sSum[4][64];
  __shared__ float sSq[4][64];

  const int tid = threadIdx.x;
  const int l = tid & 63, w = tid >> 6;

  // XCD-aware (p, y) decode
  const int ny = gridDim.x / 3;
  const int ny8 = ny & ~7;
  int p, y;
  if ((int)blockIdx.x < 3 * ny8) {
    const int g = blockIdx.x / 24, r2 = blockIdx.x % 24;
    p = r2 >> 3;
    y = g * 8 + (r2 & 7);
  } else {
    const int b2 = blockIdx.x - 3 * ny8;
    const int nt = ny - ny8;
    p = b2 / nt;
    y = ny8 + b2 % nt;
  }
  const int c0 = p * 256;
  const int r0 = y * 64;

  const int lrow = l >> 3, chunk = l & 7;
  const int g8 = (l >> 4) * 8, l15 = l & 15;
  const int rbase = 4 * (l >> 4);
  const int swz = l15 & 7;                // read-side chunk XOR (== row&7 for all frag rows)

  sG[tid] = bf2f(params[p * 512 + tid]);
  sB[tid] = bf2f(params[p * 512 + 256 + tid]);

  f32x4 acc[4][4];
#pragma unroll
  for (int m = 0; m < 4; ++m)
#pragma unroll
    for (int n = 0; n < 4; ++n)
      acc[m][n] = (f32x4){0.f, 0.f, 0.f, 0.f};

  for (int ks = 0; ks < 12; ++ks) {
    const int k0 = ks * 64;
    const int t = k0 >> 8, kc = k0 & 255;
    __syncthreads();
    // stage A (64x64): 8 segs, 2/wave; source pre-swizzled by chunk^lrow
#pragma unroll
    for (int it = 0; it < 2; ++it) {
      const int seg = w * 2 + it;
      const int row_l = seg * 8 + lrow;
      const bool valid = ((unsigned)((r0 + row_l) % 25 + t - 1) < 25u);
      const u16* src = valid
          ? xbf + (size_t)(row0 + r0 + row_l + t - 1) * 256 + kc + ((chunk ^ lrow) << 3)
          : zpad;
      gl_lds(src, &Asm[seg * 512]);
    }
    // stage B (256x64): 32 segs, 8/wave
#pragma unroll
    for (int it = 0; it < 8; ++it) {
      const int seg = w * 8 + it;
      const int row_l = seg * 8 + lrow;
      const u16* src = wT + (size_t)(c0 + row_l) * 768 + k0 + ((chunk ^ lrow) << 3);
      gl_lds(src, &Bsm[seg * 512]);
    }
    __syncthreads();

#pragma unroll
    for (int kk = 0; kk < 64; kk += 32) {
      const int c = (kk >> 3) + (l >> 4);
      const int co = ((c ^ swz) << 3);
      bf16x8 av[4], bv[4];
#pragma unroll
      for (int m = 0; m < 4; ++m)
        av[m] = *(const bf16x8*)&Asm[(m * 16 + l15) * 64 + co];
#pragma unroll
      for (int n = 0; n < 4; ++n)
        bv[n] = *(const bf16x8*)&Bsm[(w * 64 + n * 16 + l15) * 64 + co];
#pragma unroll
      for (int m = 0; m < 4; ++m)
#pragma unroll
        for (int n = 0; n < 4; ++n)
          acc[m][n] = __builtin_amdgcn_mfma_f32_16x16x32_bf16(av[m], bv[n], acc[m][n], 0, 0, 0);
    }
  }

  // ---- LN stats: per-thread partials -> 4 shuffles -> cross-wave LDS combine
#pragma unroll
  for (int m = 0; m < 4; ++m) {
#pragma unroll
    for (int r = 0; r < 4; ++r) {
      float s = 0.f, q = 0.f;
#pragma unroll
      for (int n = 0; n < 4; ++n) { const float v = acc[m][n][r]; s += v; q += v * v; }
#pragma unroll
      for (int mk = 1; mk < 16; mk <<= 1) {
        s += __shfl_xor(s, mk, 64);
        q += __shfl_xor(q, mk, 64);
      }
      if (l15 == 0) {
        const int row = m * 16 + rbase + r;
        sSum[w][row] = s;
        sSq[w][row] = q;
      }
    }
  }
  __syncthreads();

  // ---- normalize + gamma/beta + residual, store
#pragma unroll
  for (int m = 0; m < 4; ++m) {
    float mu4[4], rs4[4];
#pragma unroll
    for (int r = 0; r < 4; ++r) {
      const int row = m * 16 + rbase + r;
      const float tot = sSum[0][row] + sSum[1][row] + sSum[2][row] + sSum[3][row];
      const float tq  = sSq[0][row] + sSq[1][row] + sSq[2][row] + sSq[3][row];
      const float mu = tot * (1.f / 256.f);
      const float var = tq * (1.f / 256.f) - mu * mu;
      mu4[r] = mu;
      rs4[r] = rsqrtf(var + 1e-5f);
    }
#pragma unroll
    for (int n = 0; n < 4; ++n) {
      const int lc = w * 64 + n * 16 + l15;
      const float g = sG[lc], bb = sB[lc];
#pragma unroll
      for (int r = 0; r < 4; ++r) {
        const int row = m * 16 + rbase + r;
        const float xv = bf2f(xbf[(size_t)(row0 + r0 + row) * 256 + lc]);
        const float v = (acc[m][n][r] - mu4[r]) * rs4[r] * g + bb + xv;
        C[(size_t)(r0 + row) * 768 + c0 + lc] = f2bf(v);
      }
    }
  }
}

// ---------- MFMA GEMM (bf16 A, global_load_lds, XOR-swizzled): tiles 128 x BN ----------
template<int BN, bool HAS_BIAS, bool F32OUT>
__global__ __launch_bounds__(256) void gemm_kernel(
    const u16* __restrict__ A, int lda, long long row0,
    const u16* __restrict__ BT, int ldb,
    void* __restrict__ Cv, int ldc,
    const u16* __restrict__ bias,
    int ksteps)
{
  constexpr int NB = BN / 32;
  __shared__ __align__(16) u16 Asm[128 * 64];
  __shared__ __align__(16) u16 Bsm[BN * 64];

  const int tid = threadIdx.x;
  const int l = tid & 63;
  const int w = tid >> 6;
  const int c0 = blockIdx.x * BN;
  const int r0 = blockIdx.y * 128;
  const int wr = w >> 1, wc = w & 1;

  f32x4 acc[4][NB];
#pragma unroll
  for (int m = 0; m < 4; ++m)
#pragma unroll
    for (int n = 0; n < NB; ++n)
      acc[m][n] = (f32x4){0.f, 0.f, 0.f, 0.f};

  const int lrow = l >> 3;
  const int chunk = l & 7;
  const int l15 = l & 15;
  const int swz = l15 & 7;

  for (int ks = 0; ks < ksteps; ++ks) {
    const int k0 = ks * 64;
    __syncthreads();
#pragma unroll
    for (int it = 0; it < 4; ++it) {
      const int seg = w * 4 + it;
      const int row_l = seg * 8 + lrow;
      const u16* src = A + (size_t)(row0 + r0 + row_l) * lda + k0 + ((chunk ^ lrow) << 3);
      gl_lds(src, &Asm[seg * 512]);
    }
#pragma unroll
    for (int it = 0; it < NB; ++it) {
      const int seg = w * NB + it;
      const int row_l = seg * 8 + lrow;
      const u16* src = BT + (size_t)(c0 + row_l) * ldb + k0 + ((chunk ^ lrow) << 3);
      gl_lds(src, &Bsm[seg * 512]);
    }
    __syncthreads();

#pragma unroll
    for (int kk = 0; kk < 64; kk += 32) {
      const int c = (kk >> 3) + (l >> 4);
      const int co = ((c ^ swz) << 3);
      bf16x8 av[4], bv[NB];
#pragma unroll
      for (int m = 0; m < 4; ++m)
        av[m] = *(const bf16x8*)&Asm[(wr * 64 + m * 16 + l15) * 64 + co];
#pragma unroll
      for (int n = 0; n < NB; ++n)
        bv[n] = *(const bf16x8*)&Bsm[(wc * (BN / 2) + n * 16 + l15) * 64 + co];
#pragma unroll
      for (int m = 0; m < 4; ++m)
#pragma unroll
        for (int n = 0; n < NB; ++n)
          acc[m][n] = __builtin_amdgcn_mfma_f32_16x16x32_bf16(av[m], bv[n], acc[m][n], 0, 0, 0);
    }
  }

  const int rbase = 4 * (l >> 4);
#pragma unroll
  for (int m = 0; m < 4; ++m) {
#pragma unroll
    for (int n = 0; n < NB; ++n) {
      const int col = c0 + wc * (BN / 2) + n * 16 + l15;
      float badd = 0.f;
      if (HAS_BIAS) badd = bf2f(bias[col]);
#pragma unroll
      for (int r = 0; r < 4; ++r) {
        const int row = r0 + wr * 64 + m * 16 + rbase + r;
        const float v = acc[m][n][r] + badd;
        if constexpr (F32OUT) ((float*)Cv)[(size_t)row * ldc + col] = v;
        else                  ((u16*)Cv)[(size_t)row * ldc + col] = f2bf(v);
      }
    }
  }
}

// ---------- fused attention per batch (LN already applied to qkv) ----------
// LDS 38,848 B -> 4 blocks/CU, 4 barriers
__global__ __launch_bounds__(256) void attn_kernel(
    u16* __restrict__ qkv,                  // chunk-local [CB*25][768]; cols 0-255 get attn_out
    const u16* __restrict__ qf,             // chunk-local [CB*25][64]
    const u16* __restrict__ params)
{
  __shared__ __align__(16) char arena[38848];
  float* sS    = (float*)arena;
  u16*   sV    = (u16*)(arena + 20000);
  u16*   sQF   = (u16*)(arena + 33200);
  u16*   sWQPT = (u16*)(arena + 36800);

  const int b = blockIdx.x;
  const int tid = threadIdx.x;
  const int w = tid >> 6, l = tid & 63;
  const int g8 = (l >> 4) * 8;
  const int rbase = 4 * (l >> 4);
  const int l15 = l & 15;

  // ---- P0: stage V (LN'd), qf, wqpT
  {
    for (int i = tid; i < 800; i += 256) {
      const int m = i >> 5, c8 = (i & 31) * 8;
      *(uint4*)&sV[m * 264 + c8] =
          *(const uint4*)(qkv + (size_t)(b * 25 + m) * 768 + 512 + c8);
    }
    for (int i = tid; i < 200; i += 256) {
      const int r = i >> 3, c8 = (i & 7) * 8;
      *(uint4*)&sQF[r * 72 + c8] = *(const uint4*)(qf + (size_t)b * 1600 + r * 64 + c8);
    }
    for (int i = tid; i < 128; i += 256)
      ((uint4*)sWQPT)[i] = ((const uint4*)(params + 7776))[i];
  }
  __syncthreads();

  // ---- P1: dyn-bias tiles in registers + scores via MFMA (Q/K direct from global)
  f32x4 dt[10];
  {
    const bf16x8 bv0 = *(const bf16x8*)&sWQPT[l15 * 64 + g8];
    const bf16x8 bv1 = *(const bf16x8*)&sWQPT[l15 * 64 + 32 + g8];
#pragma unroll
    for (int ti = 0; ti < 10; ++ti) {
      const int p0 = (ti * 4 + w) * 16;
      int p = p0 + l15; if (p > 624) p = 624;
      const int n = p / 25, m = p % 25;
      const uint4 qn0 = *(const uint4*)&sQF[n * 72 + g8];
      const uint4 qn1 = *(const uint4*)&sQF[n * 72 + 32 + g8];
      const uint4 qm0 = *(const uint4*)&sQF[m * 72 + g8];
      const uint4 qm1 = *(const uint4*)&sQF[m * 72 + 32 + g8];
      u32 a0[4], a1[4];
      a0[0] = tanh2(qn0.x, qm0.x); a0[1] = tanh2(qn0.y, qm0.y);
      a0[2] = tanh2(qn0.z, qm0.z); a0[3] = tanh2(qn0.w, qm0.w);
      a1[0] = tanh2(qn1.x, qm1.x); a1[1] = tanh2(qn1.y, qm1.y);
      a1[2] = tanh2(qn1.z, qm1.z); a1[3] = tanh2(qn1.w, qm1.w);
      const bf16x8 av0 = __builtin_bit_cast(bf16x8, *(uint4*)a0);
      const bf16x8 av1 = __builtin_bit_cast(bf16x8, *(uint4*)a1);
      f32x4 d = (f32x4){0.f, 0.f, 0.f, 0.f};
      d = __builtin_amdgcn_mfma_f32_16x16x32_bf16(av0, bv0, d, 0, 0, 0);
      d = __builtin_amdgcn_mfma_f32_16x16x32_bf16(av1, bv1, d, 0, 0, 0);
      dt[ti] = d;
    }
    // scores: 2 heads/wave; fragments straight from global (16 rows x 64B pattern)
    bf16x8 zf8;
#pragma unroll
    for (int j = 0; j < 8; ++j) zf8[j] = (__bf16)0.f;
#pragma unroll
    for (int hh = 0; hh < 2; ++hh) {
      const int h = 2 * w + hh;
      bf16x8 qa[2], kb[2];
#pragma unroll
      for (int t = 0; t < 2; ++t) {
        const int row = l15 + 16 * t;
        if (row < 25) {
          const u16* base = qkv + (size_t)(b * 25 + row) * 768 + h * 32 + g8;
          qa[t] = *(const bf16x8*)base;
          kb[t] = *(const bf16x8*)(base + 256);
        } else { qa[t] = zf8; kb[t] = zf8; }
      }
#pragma unroll
      for (int tn = 0; tn < 2; ++tn)
#pragma unroll
        for (int tm = 0; tm < 2; ++tm) {
          f32x4 d = __builtin_amdgcn_mfma_f32_16x16x32_bf16(
              qa[tn], kb[tm], (f32x4){0.f, 0.f, 0.f, 0.f}, 0, 0, 0);
          const int m = l15 + 16 * tm;
#pragma unroll
          for (int r = 0; r < 4; ++r) {
            const int n = rbase + r + 16 * tn;
            if (n < 25 && m < 25) {
              const int idx = h * 625 + n * 25 + m;
              sS[idx] = d[r] * 0.17677669529663687f + bf2f(params[1928 + idx]);
            }
          }
        }
    }
  }
  __syncthreads();

  // ---- P2: scatter-add dyn tiles into sS
  {
    if (l15 < 8) {
      const int h = l15;
#pragma unroll
      for (int ti = 0; ti < 10; ++ti) {
        const int p0 = (ti * 4 + w) * 16;
#pragma unroll
        for (int r = 0; r < 4; ++r) {
          const int p = p0 + rbase + r;
          if (p < 625) sS[h * 625 + p] += dt[ti][r];
        }
      }
    }
  }
  __syncthreads();

  // ---- P3: softmax over m
  {
    for (int u = tid; u < 200; u += 256) {
      const int h = u / 25, n = u % 25;
      float* rp = &sS[h * 625 + n * 25];
      float mx = -1e30f;
#pragma unroll
      for (int m = 0; m < 25; ++m) mx = fmaxf(mx, rp[m]);
      float ssum = 0.f;
#pragma unroll
      for (int m = 0; m < 25; ++m) { rp[m] = __expf(rp[m] - mx); ssum += rp[m]; }
      const float inv = __builtin_amdgcn_rcpf(ssum);
#pragma unroll
      for (int m = 0; m < 25; ++m) rp[m] *= inv;
    }
  }
  __syncthreads();

  // ---- P4: PV via MFMA -> global qkv cols 0-255
  {
#pragma unroll
    for (int hh = 0; hh < 2; ++hh) {
      const int h = 2 * w + hh;
      bf16x8 pa[2], vb[2];
#pragma unroll
      for (int t = 0; t < 2; ++t) {
        const int n = l15 + 16 * t;
#pragma unroll
        for (int j = 0; j < 8; ++j) {
          const int m = g8 + j;
          const float pv = (n < 25 && m < 25) ? sS[h * 625 + n * 25 + m] : 0.f;
          pa[t][j] = (__bf16)pv;
        }
      }
#pragma unroll
      for (int t = 0; t < 2; ++t) {
        const int dcol = l15 + 16 * t;
#pragma unroll
        for (int j = 0; j < 8; ++j) {
          const int m = g8 + j;
          vb[t][j] = (m < 25)
              ? __builtin_bit_cast(__bf16, sV[m * 264 + h * 32 + dcol])
              : (__bf16)0.f;
        }
      }
#pragma unroll
      for (int tn = 0; tn < 2; ++tn)
#pragma unroll
        for (int td = 0; td < 2; ++td) {
          f32x4 d = __builtin_amdgcn_mfma_f32_16x16x32_bf16(
              pa[tn], vb[td], (f32x4){0.f, 0.f, 0.f, 0.f}, 0, 0, 0);
          const int dcol = l15 + 16 * td;
#pragma unroll
          for (int r = 0; r < 4; ++r) {
            const int n = rbase + r + 16 * tn;
            if (n < 25)
              qkv[(size_t)(b * 25 + n) * 768 + h * 32 + dcol] = f2bf(d[r]);
          }
        }
    }
  }
}

// ---------- launch ----------
extern "C" void kernel_launch(void* const* d_in, const int* in_sizes, int n_in,
                              void* d_out, int out_size, void* d_ws, size_t ws_size,
                              hipStream_t stream) {
  (void)in_sizes; (void)n_in; (void)out_size;
  const float* x    = (const float*)d_in[0];
  const float* wq   = (const float*)d_in[1];
  const float* wk   = (const float*)d_in[2];
  const float* wv   = (const float*)d_in[3];
  const float* lnqg = (const float*)d_in[4];
  const float* lnqb = (const float*)d_in[5];
  const float* lnkg = (const float*)d_in[6];
  const float* lnkb = (const float*)d_in[7];
  const float* lnvg = (const float*)d_in[8];
  const float* lnvb = (const float*)d_in[9];
  const float* relt = (const float*)d_in[10];
  const float* gbias= (const float*)d_in[11];
  const float* alph = (const float*)d_in[12];
  const float* wqf  = (const float*)d_in[13];
  const float* bqf  = (const float*)d_in[14];
  const float* wqp  = (const float*)d_in[15];
  const float* bqp  = (const float*)d_in[16];
  const float* wo   = (const float*)d_in[17];
  const float* bo   = (const float*)d_in[18];

  char* ws = (char*)d_ws;
  u16* params = (u16*)(ws + 0);
  u16* wT     = (u16*)(ws + 32768);
  u16* woT    = (u16*)(ws + 1212416);
  u16* wqfT   = (u16*)(ws + 1343488);
  const size_t fixed_bytes = 1376256;
  const size_t xbf_bytes = 52428800;
  const size_t per_batch = 41600;   // qkv 38400 + qf 3200 bytes
  u16* zpad = params + 8800;

  int CB = 4096;
  while (CB > 128 && fixed_bytes + xbf_bytes + (size_t)CB * per_batch > ws_size) CB >>= 1;
  const int nchunks = 4096 / CB;
  const int rows = CB * 25;

  u16* x_bf = (u16*)(ws + fixed_bytes);
  const size_t chunk_off = fixed_bytes + xbf_bytes;
  u16* qkv_c = (u16*)(ws + chunk_off);
  u16* qf_c  = (u16*)(ws + chunk_off + (size_t)CB * 38400);
  float* outf = (float*)d_out;

  prep_kernel<<<2659, 256, 0, stream>>>(
      wq, wk, wv, wo, wqf, lnqg, lnqb, lnkg, lnkb, lnvg, lnvb,
      relt, gbias, alph, wqp, bqp, bqf, bo,
      wT, woT, wqfT, params);
  xconv_kernel<<<12800, 256, 0, stream>>>(x, x_bf);

  for (int c = 0; c < nchunks; ++c) {
    const long long R0 = (long long)c * rows;

    // conv q/k/v projection + fused LN + residual (XCD-aware 1-D grid)
    convln_kernel<<<3 * (rows / 64), 256, 0, stream>>>(
        x_bf, R0, wT, qkv_c, params, zpad);

    // qf: [rows x 64] = x @ wqf + bqf
    gemm_kernel<64, true, false><<<dim3(1, rows / 128), 256, 0, stream>>>(
        x_bf, 256, R0, wqfT, 256, qf_c, 64, params + 7456, 4);

    // fused attention per batch
    attn_kernel<<<CB, 256, 0, stream>>>(qkv_c, qf_c, params);

    // output projection: [rows x 256] = attn_out @ wo + bo (f32 out)
    gemm_kernel<128, true, true><<<dim3(2, rows / 128), 256, 0, stream>>>(
        qkv_c, 768, 0, woT, 256, outf + (size_t)R0 * 256, 256, params + 7520, 4);
  }
}

// Round 21
// 370.682 us; speedup vs baseline: 1.9328x; 1.0138x over previous
//
#include <hip/hip_runtime.h>
#include <hip/hip_bf16.h>
#include <stdint.h>

using u16 = unsigned short;
using u32 = unsigned int;

typedef __attribute__((ext_vector_type(8))) __bf16 bf16x8;
typedef __attribute__((ext_vector_type(4))) float f32x4;

// ---------- helpers ----------
__device__ __forceinline__ float bf2f(u16 h) {
  u32 u = ((u32)h) << 16;
  return __builtin_bit_cast(float, u);
}
__device__ __forceinline__ u16 f2bf(float f) {
  u32 u = __builtin_bit_cast(u32, f);
  u += 0x7fffu + ((u >> 16) & 1u);   // RNE
  return (u16)(u >> 16);
}
__device__ __forceinline__ float blo(u32 u) { return __builtin_bit_cast(float, u << 16); }
__device__ __forceinline__ float bhi(u32 u) { return __builtin_bit_cast(float, u & 0xffff0000u); }

__device__ __forceinline__ uint4 cvt8(const float* s) {
  float4 f0 = *(const float4*)s;
  float4 f1 = *(const float4*)(s + 4);
  uint4 r;
  r.x = (u32)f2bf(f0.x) | ((u32)f2bf(f0.y) << 16);
  r.y = (u32)f2bf(f0.z) | ((u32)f2bf(f0.w) << 16);
  r.z = (u32)f2bf(f1.x) | ((u32)f2bf(f1.y) << 16);
  r.w = (u32)f2bf(f1.z) | ((u32)f2bf(f1.w) << 16);
  return r;
}

// tanh of packed bf16 differences
__device__ __forceinline__ u32 tanh2(u32 a, u32 b) {
  const float d0 = blo(a) - blo(b);
  const float d1 = bhi(a) - bhi(b);
  const float e0 = __expf(2.f * d0), e1 = __expf(2.f * d1);
  const float t0 = 1.f - 2.f * __builtin_amdgcn_rcpf(e0 + 1.f);
  const float t1 = 1.f - 2.f * __builtin_amdgcn_rcpf(e1 + 1.f);
  return (u32)f2bf(t0) | ((u32)f2bf(t1) << 16);
}

__device__ __forceinline__ void gl_lds(const u16* gsrc, u16* ldsbase) {
  __builtin_amdgcn_global_load_lds(
      (const __attribute__((address_space(1))) u32*)gsrc,
      (__attribute__((address_space(3))) u32*)ldsbase, 16, 0, 0);
}

// ---------- ws layout (bytes) ----------
//  params @ 0 (8864 u16 = 17728, pad 32768) | wT @ 32768 (1,179,648)
//  woT @ 1,212,416 (131,072) | wqfT @ 1,343,488 (32,768)  -> fixed = 1,376,256
//  x_bf @ fixed (52,428,800) | chunk after: qkv CB*38400, qf CB*3200
// params (u16): LN 0(1536) REL 1536(392) GBC 1928(5000 = rel+alpha*gbias+bqp)
//  ALPHA 6928(8) WQP 6936(512) BQP 7448(8) BQF 7456(64) BO 7520(256)
//  WQPT16 7776(1024 = [16 cols][64 k], cols 8-15 zero) ZPAD 8800(64 zeros)

// ---------- prep ----------
__global__ __launch_bounds__(256) void prep_kernel(
    const float* __restrict__ wq, const float* __restrict__ wk, const float* __restrict__ wv,
    const float* __restrict__ wo, const float* __restrict__ wqf,
    const float* __restrict__ lnqg, const float* __restrict__ lnqb,
    const float* __restrict__ lnkg, const float* __restrict__ lnkb,
    const float* __restrict__ lnvg, const float* __restrict__ lnvb,
    const float* __restrict__ relt, const float* __restrict__ gbias,
    const float* __restrict__ alphap,
    const float* __restrict__ wqp, const float* __restrict__ bqp,
    const float* __restrict__ bqf, const float* __restrict__ bo,
    u16* __restrict__ wT, u16* __restrict__ woT,
    u16* __restrict__ wqfT, u16* __restrict__ params)
{
  long long j = (long long)blockIdx.x * 256 + threadIdx.x;
  if (j < 589824) {                 // wT[col][k] = w_p[o][i][t], k=t*256+i
    int col = (int)(j / 768), k = (int)(j % 768);
    int p = col >> 8, o = col & 255, t = k >> 8, i = k & 255;
    const float* w = (p == 0) ? wq : (p == 1) ? wk : wv;
    wT[j] = f2bf(w[o * 768 + i * 3 + t]);
    return;
  }
  j -= 589824;
  if (j < 65536) {                  // woT[n][k] = wo[k][n]
    int n = (int)(j >> 8), k = (int)(j & 255);
    woT[j] = f2bf(wo[k * 256 + n]);
    return;
  }
  j -= 65536;
  if (j < 16384) {                  // wqfT[col][k] = wqf[k][col]
    int col = (int)(j >> 8), k = (int)(j & 255);
    wqfT[j] = f2bf(wqf[k * 64 + col]);
    return;
  }
  j -= 16384;
  if (j < 8864) {
    int t = (int)j;
    if (t >= 8800) { params[t] = 0; return; }               // zpad
    if (t >= 7776) {                                        // wqpT16[col][k]
      int t2 = t - 7776;
      int col = t2 >> 6, k = t2 & 63;
      params[t] = (col < 8) ? f2bf(wqp[k * 8 + col]) : (u16)0;
      return;
    }
    if (t >= 1928 && t < 6928) {    // combined bias: rel + alpha*gbias + bqp
      int idx = t - 1928;
      int h = idx / 625, rem = idx % 625, n = rem / 25, m = rem % 25;
      params[t] = f2bf(gbias[idx] * alphap[0] + relt[(n - m + 24) * 8 + h] + bqp[h]);
      return;
    }
    const float* src; int si;
    if (t < 1536) {
      int a = t >> 8, c = t & 255;
      src = (a == 0) ? lnqg : (a == 1) ? lnqb : (a == 2) ? lnkg
          : (a == 3) ? lnkb : (a == 4) ? lnvg : lnvb;
      si = c;
    } else if (t < 1928) { src = relt;  si = t - 1536; }
    else if (t < 6936)   { src = alphap; si = 0; }
    else if (t < 7448)   { src = wqp;   si = t - 6936; }
    else if (t < 7456)   { src = bqp;   si = t - 7448; }
    else if (t < 7520)   { src = bqf;   si = t - 7456; }
    else                 { src = bo;    si = t - 7520; }
    params[t] = f2bf(src[si]);
  }
}

// ---------- xconv: x (f32) -> x_bf ----------
__global__ __launch_bounds__(256) void xconv_kernel(
    const float* __restrict__ x, u16* __restrict__ xbf)
{
  const long long i = ((long long)blockIdx.x * 256 + threadIdx.x) * 8;
  *(uint4*)&xbf[i] = cvt8(x + i);
}

// ---------- convln: conv GEMM (BM=64 x BN=256) + fused LN + residual ----------
// 256 threads = 4 waves; wave w owns 64 rows x cols [w*64, w*64+64).
// XOR-swizzled LDS (pre-swizzled global source, unswizzled reads).
// 1-D grid (3*ny blocks) with XCD-aware decode: the 3 projections of the same
// y-tile get bids differing by 8 -> same XCD (bid%8) -> shared-A L2 hits.
__global__ __launch_bounds__(256) void convln_kernel(
    const u16* __restrict__ xbf, long long row0,
    const u16* __restrict__ wT,
    u16* __restrict__ C,                 // chunk-local qkv [rows][768]
    const u16* __restrict__ params,
    const u16* __restrict__ zpad)
{
  __shared__ __align__(16) u16 Asm[64 * 64];
  __shared__ __align__(16) u16 Bsm[256 * 64];
  __shared__ float sG[256];
  __shared__ float sB[256];
  __shared__ float sSum[4][64];
  __shared__ float sSq[4][64];

  const int tid = threadIdx.x;
  const int l = tid & 63, w = tid >> 6;

  // XCD-aware (p, y) decode
  const int ny = gridDim.x / 3;
  const int ny8 = ny & ~7;
  int p, y;
  if ((int)blockIdx.x < 3 * ny8) {
    const int g = blockIdx.x / 24, r2 = blockIdx.x % 24;
    p = r2 >> 3;
    y = g * 8 + (r2 & 7);
  } else {
    const int b2 = blockIdx.x - 3 * ny8;
    const int nt = ny - ny8;
    p = b2 / nt;
    y = ny8 + b2 % nt;
  }
  const int c0 = p * 256;
  const int r0 = y * 64;

  const int lrow = l >> 3, chunk = l & 7;
  const int g8 = (l >> 4) * 8, l15 = l & 15;
  const int rbase = 4 * (l >> 4);
  const int swz = l15 & 7;                // read-side chunk XOR (== row&7 for all frag rows)

  sG[tid] = bf2f(params[p * 512 + tid]);
  sB[tid] = bf2f(params[p * 512 + 256 + tid]);

  f32x4 acc[4][4];
#pragma unroll
  for (int m = 0; m < 4; ++m)
#pragma unroll
    for (int n = 0; n < 4; ++n)
      acc[m][n] = (f32x4){0.f, 0.f, 0.f, 0.f};

  for (int ks = 0; ks < 12; ++ks) {
    const int k0 = ks * 64;
    const int t = k0 >> 8, kc = k0 & 255;
    __syncthreads();
    // stage A (64x64): 8 segs, 2/wave; source pre-swizzled by chunk^lrow
#pragma unroll
    for (int it = 0; it < 2; ++it) {
      const int seg = w * 2 + it;
      const int row_l = seg * 8 + lrow;
      const bool valid = ((unsigned)((r0 + row_l) % 25 + t - 1) < 25u);
      const u16* src = valid
          ? xbf + (size_t)(row0 + r0 + row_l + t - 1) * 256 + kc + ((chunk ^ lrow) << 3)
          : zpad;
      gl_lds(src, &Asm[seg * 512]);
    }
    // stage B (256x64): 32 segs, 8/wave
#pragma unroll
    for (int it = 0; it < 8; ++it) {
      const int seg = w * 8 + it;
      const int row_l = seg * 8 + lrow;
      const u16* src = wT + (size_t)(c0 + row_l) * 768 + k0 + ((chunk ^ lrow) << 3);
      gl_lds(src, &Bsm[seg * 512]);
    }
    __syncthreads();

#pragma unroll
    for (int kk = 0; kk < 64; kk += 32) {
      const int c = (kk >> 3) + (l >> 4);
      const int co = ((c ^ swz) << 3);
      bf16x8 av[4], bv[4];
#pragma unroll
      for (int m = 0; m < 4; ++m)
        av[m] = *(const bf16x8*)&Asm[(m * 16 + l15) * 64 + co];
#pragma unroll
      for (int n = 0; n < 4; ++n)
        bv[n] = *(const bf16x8*)&Bsm[(w * 64 + n * 16 + l15) * 64 + co];
#pragma unroll
      for (int m = 0; m < 4; ++m)
#pragma unroll
        for (int n = 0; n < 4; ++n)
          acc[m][n] = __builtin_amdgcn_mfma_f32_16x16x32_bf16(av[m], bv[n], acc[m][n], 0, 0, 0);
    }
  }

  // ---- LN stats: per-thread partials -> 4 shuffles -> cross-wave LDS combine
#pragma unroll
  for (int m = 0; m < 4; ++m) {
#pragma unroll
    for (int r = 0; r < 4; ++r) {
      float s = 0.f, q = 0.f;
#pragma unroll
      for (int n = 0; n < 4; ++n) { const float v = acc[m][n][r]; s += v; q += v * v; }
#pragma unroll
      for (int mk = 1; mk < 16; mk <<= 1) {
        s += __shfl_xor(s, mk, 64);
        q += __shfl_xor(q, mk, 64);
      }
      if (l15 == 0) {
        const int row = m * 16 + rbase + r;
        sSum[w][row] = s;
        sSq[w][row] = q;
      }
    }
  }
  __syncthreads();

  // ---- normalize + gamma/beta + residual, store
#pragma unroll
  for (int m = 0; m < 4; ++m) {
    float mu4[4], rs4[4];
#pragma unroll
    for (int r = 0; r < 4; ++r) {
      const int row = m * 16 + rbase + r;
      const float tot = sSum[0][row] + sSum[1][row] + sSum[2][row] + sSum[3][row];
      const float tq  = sSq[0][row] + sSq[1][row] + sSq[2][row] + sSq[3][row];
      const float mu = tot * (1.f / 256.f);
      const float var = tq * (1.f / 256.f) - mu * mu;
      mu4[r] = mu;
      rs4[r] = rsqrtf(var + 1e-5f);
    }
#pragma unroll
    for (int n = 0; n < 4; ++n) {
      const int lc = w * 64 + n * 16 + l15;
      const float g = sG[lc], bb = sB[lc];
#pragma unroll
      for (int r = 0; r < 4; ++r) {
        const int row = m * 16 + rbase + r;
        const float xv = bf2f(xbf[(size_t)(row0 + r0 + row) * 256 + lc]);
        const float v = (acc[m][n][r] - mu4[r]) * rs4[r] * g + bb + xv;
        C[(size_t)(r0 + row) * 768 + c0 + lc] = f2bf(v);
      }
    }
  }
}

// ---------- MFMA GEMM (bf16 A, global_load_lds, XOR-swizzled): tiles 128 x BN ----------
// XCDP: 1-D grid, col-tiles of the same y-row-panel co-located on one XCD.
template<int BN, bool HAS_BIAS, bool F32OUT, bool XCDP>
__global__ __launch_bounds__(256) void gemm_kernel(
    const u16* __restrict__ A, int lda, long long row0,
    const u16* __restrict__ BT, int ldb,
    void* __restrict__ Cv, int ldc,
    const u16* __restrict__ bias,
    int ksteps, int ncols)
{
  constexpr int NB = BN / 32;
  __shared__ __align__(16) u16 Asm[128 * 64];
  __shared__ __align__(16) u16 Bsm[BN * 64];

  const int tid = threadIdx.x;
  const int l = tid & 63;
  const int w = tid >> 6;

  int c0, r0;
  if constexpr (XCDP) {
    const int ny = gridDim.x / ncols;
    const int ny8 = ny & ~7;
    const int grp = ncols * 8;
    int cx, y;
    if ((int)blockIdx.x < ncols * ny8) {
      const int g = blockIdx.x / grp, r2 = blockIdx.x % grp;
      cx = r2 >> 3;
      y = g * 8 + (r2 & 7);
    } else {
      const int b2 = blockIdx.x - ncols * ny8;
      const int nt = ny - ny8;
      cx = b2 / nt;
      y = ny8 + b2 % nt;
    }
    c0 = cx * BN;
    r0 = y * 128;
  } else {
    c0 = blockIdx.x * BN;
    r0 = blockIdx.y * 128;
  }
  const int wr = w >> 1, wc = w & 1;

  f32x4 acc[4][NB];
#pragma unroll
  for (int m = 0; m < 4; ++m)
#pragma unroll
    for (int n = 0; n < NB; ++n)
      acc[m][n] = (f32x4){0.f, 0.f, 0.f, 0.f};

  const int lrow = l >> 3;
  const int chunk = l & 7;
  const int l15 = l & 15;
  const int swz = l15 & 7;

  for (int ks = 0; ks < ksteps; ++ks) {
    const int k0 = ks * 64;
    __syncthreads();
#pragma unroll
    for (int it = 0; it < 4; ++it) {
      const int seg = w * 4 + it;
      const int row_l = seg * 8 + lrow;
      const u16* src = A + (size_t)(row0 + r0 + row_l) * lda + k0 + ((chunk ^ lrow) << 3);
      gl_lds(src, &Asm[seg * 512]);
    }
#pragma unroll
    for (int it = 0; it < NB; ++it) {
      const int seg = w * NB + it;
      const int row_l = seg * 8 + lrow;
      const u16* src = BT + (size_t)(c0 + row_l) * ldb + k0 + ((chunk ^ lrow) << 3);
      gl_lds(src, &Bsm[seg * 512]);
    }
    __syncthreads();

#pragma unroll
    for (int kk = 0; kk < 64; kk += 32) {
      const int c = (kk >> 3) + (l >> 4);
      const int co = ((c ^ swz) << 3);
      bf16x8 av[4], bv[NB];
#pragma unroll
      for (int m = 0; m < 4; ++m)
        av[m] = *(const bf16x8*)&Asm[(wr * 64 + m * 16 + l15) * 64 + co];
#pragma unroll
      for (int n = 0; n < NB; ++n)
        bv[n] = *(const bf16x8*)&Bsm[(wc * (BN / 2) + n * 16 + l15) * 64 + co];
#pragma unroll
      for (int m = 0; m < 4; ++m)
#pragma unroll
        for (int n = 0; n < NB; ++n)
          acc[m][n] = __builtin_amdgcn_mfma_f32_16x16x32_bf16(av[m], bv[n], acc[m][n], 0, 0, 0);
    }
  }

  const int rbase = 4 * (l >> 4);
#pragma unroll
  for (int m = 0; m < 4; ++m) {
#pragma unroll
    for (int n = 0; n < NB; ++n) {
      const int col = c0 + wc * (BN / 2) + n * 16 + l15;
      float badd = 0.f;
      if (HAS_BIAS) badd = bf2f(bias[col]);
#pragma unroll
      for (int r = 0; r < 4; ++r) {
        const int row = r0 + wr * 64 + m * 16 + rbase + r;
        const float v = acc[m][n][r] + badd;
        if constexpr (F32OUT) ((float*)Cv)[(size_t)row * ldc + col] = v;
        else                  ((u16*)Cv)[(size_t)row * ldc + col] = f2bf(v);
      }
    }
  }
}

// ---------- fused attention per batch (LN already applied to qkv) ----------
// LDS 38,848 B -> 4 blocks/CU, 4 barriers
__global__ __launch_bounds__(256) void attn_kernel(
    u16* __restrict__ qkv,                  // chunk-local [CB*25][768]; cols 0-255 get attn_out
    const u16* __restrict__ qf,             // chunk-local [CB*25][64]
    const u16* __restrict__ params)
{
  __shared__ __align__(16) char arena[38848];
  float* sS    = (float*)arena;
  u16*   sV    = (u16*)(arena + 20000);
  u16*   sQF   = (u16*)(arena + 33200);
  u16*   sWQPT = (u16*)(arena + 36800);

  const int b = blockIdx.x;
  const int tid = threadIdx.x;
  const int w = tid >> 6, l = tid & 63;
  const int g8 = (l >> 4) * 8;
  const int rbase = 4 * (l >> 4);
  const int l15 = l & 15;

  // ---- P0: stage V (LN'd), qf, wqpT
  {
    for (int i = tid; i < 800; i += 256) {
      const int m = i >> 5, c8 = (i & 31) * 8;
      *(uint4*)&sV[m * 264 + c8] =
          *(const uint4*)(qkv + (size_t)(b * 25 + m) * 768 + 512 + c8);
    }
    for (int i = tid; i < 200; i += 256) {
      const int r = i >> 3, c8 = (i & 7) * 8;
      *(uint4*)&sQF[r * 72 + c8] = *(const uint4*)(qf + (size_t)b * 1600 + r * 64 + c8);
    }
    for (int i = tid; i < 128; i += 256)
      ((uint4*)sWQPT)[i] = ((const uint4*)(params + 7776))[i];
  }
  __syncthreads();

  // ---- P1: dyn-bias tiles in registers + scores via MFMA (Q/K direct from global)
  f32x4 dt[10];
  {
    const bf16x8 bv0 = *(const bf16x8*)&sWQPT[l15 * 64 + g8];
    const bf16x8 bv1 = *(const bf16x8*)&sWQPT[l15 * 64 + 32 + g8];
#pragma unroll
    for (int ti = 0; ti < 10; ++ti) {
      const int p0 = (ti * 4 + w) * 16;
      int p = p0 + l15; if (p > 624) p = 624;
      const int n = p / 25, m = p % 25;
      const uint4 qn0 = *(const uint4*)&sQF[n * 72 + g8];
      const uint4 qn1 = *(const uint4*)&sQF[n * 72 + 32 + g8];
      const uint4 qm0 = *(const uint4*)&sQF[m * 72 + g8];
      const uint4 qm1 = *(const uint4*)&sQF[m * 72 + 32 + g8];
      u32 a0[4], a1[4];
      a0[0] = tanh2(qn0.x, qm0.x); a0[1] = tanh2(qn0.y, qm0.y);
      a0[2] = tanh2(qn0.z, qm0.z); a0[3] = tanh2(qn0.w, qm0.w);
      a1[0] = tanh2(qn1.x, qm1.x); a1[1] = tanh2(qn1.y, qm1.y);
      a1[2] = tanh2(qn1.z, qm1.z); a1[3] = tanh2(qn1.w, qm1.w);
      const bf16x8 av0 = __builtin_bit_cast(bf16x8, *(uint4*)a0);
      const bf16x8 av1 = __builtin_bit_cast(bf16x8, *(uint4*)a1);
      f32x4 d = (f32x4){0.f, 0.f, 0.f, 0.f};
      d = __builtin_amdgcn_mfma_f32_16x16x32_bf16(av0, bv0, d, 0, 0, 0);
      d = __builtin_amdgcn_mfma_f32_16x16x32_bf16(av1, bv1, d, 0, 0, 0);
      dt[ti] = d;
    }
    // scores: 2 heads/wave; fragments straight from global (16 rows x 64B pattern)
    bf16x8 zf8;
#pragma unroll
    for (int j = 0; j < 8; ++j) zf8[j] = (__bf16)0.f;
#pragma unroll
    for (int hh = 0; hh < 2; ++hh) {
      const int h = 2 * w + hh;
      bf16x8 qa[2], kb[2];
#pragma unroll
      for (int t = 0; t < 2; ++t) {
        const int row = l15 + 16 * t;
        if (row < 25) {
          const u16* base = qkv + (size_t)(b * 25 + row) * 768 + h * 32 + g8;
          qa[t] = *(const bf16x8*)base;
          kb[t] = *(const bf16x8*)(base + 256);
        } else { qa[t] = zf8; kb[t] = zf8; }
      }
#pragma unroll
      for (int tn = 0; tn < 2; ++tn)
#pragma unroll
        for (int tm = 0; tm < 2; ++tm) {
          f32x4 d = __builtin_amdgcn_mfma_f32_16x16x32_bf16(
              qa[tn], kb[tm], (f32x4){0.f, 0.f, 0.f, 0.f}, 0, 0, 0);
          const int m = l15 + 16 * tm;
#pragma unroll
          for (int r = 0; r < 4; ++r) {
            const int n = rbase + r + 16 * tn;
            if (n < 25 && m < 25) {
              const int idx = h * 625 + n * 25 + m;
              sS[idx] = d[r] * 0.17677669529663687f + bf2f(params[1928 + idx]);
            }
          }
        }
    }
  }
  __syncthreads();

  // ---- P2: scatter-add dyn tiles into sS
  {
    if (l15 < 8) {
      const int h = l15;
#pragma unroll
      for (int ti = 0; ti < 10; ++ti) {
        const int p0 = (ti * 4 + w) * 16;
#pragma unroll
        for (int r = 0; r < 4; ++r) {
          const int p = p0 + rbase + r;
          if (p < 625) sS[h * 625 + p] += dt[ti][r];
        }
      }
    }
  }
  __syncthreads();

  // ---- P3: softmax over m
  {
    for (int u = tid; u < 200; u += 256) {
      const int h = u / 25, n = u % 25;
      float* rp = &sS[h * 625 + n * 25];
      float mx = -1e30f;
#pragma unroll
      for (int m = 0; m < 25; ++m) mx = fmaxf(mx, rp[m]);
      float ssum = 0.f;
#pragma unroll
      for (int m = 0; m < 25; ++m) { rp[m] = __expf(rp[m] - mx); ssum += rp[m]; }
      const float inv = __builtin_amdgcn_rcpf(ssum);
#pragma unroll
      for (int m = 0; m < 25; ++m) rp[m] *= inv;
    }
  }
  __syncthreads();

  // ---- P4: PV via MFMA -> global qkv cols 0-255
  {
#pragma unroll
    for (int hh = 0; hh < 2; ++hh) {
      const int h = 2 * w + hh;
      bf16x8 pa[2], vb[2];
#pragma unroll
      for (int t = 0; t < 2; ++t) {
        const int n = l15 + 16 * t;
#pragma unroll
        for (int j = 0; j < 8; ++j) {
          const int m = g8 + j;
          const float pv = (n < 25 && m < 25) ? sS[h * 625 + n * 25 + m] : 0.f;
          pa[t][j] = (__bf16)pv;
        }
      }
#pragma unroll
      for (int t = 0; t < 2; ++t) {
        const int dcol = l15 + 16 * t;
#pragma unroll
        for (int j = 0; j < 8; ++j) {
          const int m = g8 + j;
          vb[t][j] = (m < 25)
              ? __builtin_bit_cast(__bf16, sV[m * 264 + h * 32 + dcol])
              : (__bf16)0.f;
        }
      }
#pragma unroll
      for (int tn = 0; tn < 2; ++tn)
#pragma unroll
        for (int td = 0; td < 2; ++td) {
          f32x4 d = __builtin_amdgcn_mfma_f32_16x16x32_bf16(
              pa[tn], vb[td], (f32x4){0.f, 0.f, 0.f, 0.f}, 0, 0, 0);
          const int dcol = l15 + 16 * td;
#pragma unroll
          for (int r = 0; r < 4; ++r) {
            const int n = rbase + r + 16 * tn;
            if (n < 25)
              qkv[(size_t)(b * 25 + n) * 768 + h * 32 + dcol] = f2bf(d[r]);
          }
        }
    }
  }
}

// ---------- launch ----------
extern "C" void kernel_launch(void* const* d_in, const int* in_sizes, int n_in,
                              void* d_out, int out_size, void* d_ws, size_t ws_size,
                              hipStream_t stream) {
  (void)in_sizes; (void)n_in; (void)out_size;
  const float* x    = (const float*)d_in[0];
  const float* wq   = (const float*)d_in[1];
  const float* wk   = (const float*)d_in[2];
  const float* wv   = (const float*)d_in[3];
  const float* lnqg = (const float*)d_in[4];
  const float* lnqb = (const float*)d_in[5];
  const float* lnkg = (const float*)d_in[6];
  const float* lnkb = (const float*)d_in[7];
  const float* lnvg = (const float*)d_in[8];
  const float* lnvb = (const float*)d_in[9];
  const float* relt = (const float*)d_in[10];
  const float* gbias= (const float*)d_in[11];
  const float* alph = (const float*)d_in[12];
  const float* wqf  = (const float*)d_in[13];
  const float* bqf  = (const float*)d_in[14];
  const float* wqp  = (const float*)d_in[15];
  const float* bqp  = (const float*)d_in[16];
  const float* wo   = (const float*)d_in[17];
  const float* bo   = (const float*)d_in[18];

  char* ws = (char*)d_ws;
  u16* params = (u16*)(ws + 0);
  u16* wT     = (u16*)(ws + 32768);
  u16* woT    = (u16*)(ws + 1212416);
  u16* wqfT   = (u16*)(ws + 1343488);
  const size_t fixed_bytes = 1376256;
  const size_t xbf_bytes = 52428800;
  const size_t per_batch = 41600;   // qkv 38400 + qf 3200 bytes
  u16* zpad = params + 8800;

  int CB = 4096;
  while (CB > 128 && fixed_bytes + xbf_bytes + (size_t)CB * per_batch > ws_size) CB >>= 1;
  const int nchunks = 4096 / CB;
  const int rows = CB * 25;

  u16* x_bf = (u16*)(ws + fixed_bytes);
  const size_t chunk_off = fixed_bytes + xbf_bytes;
  u16* qkv_c = (u16*)(ws + chunk_off);
  u16* qf_c  = (u16*)(ws + chunk_off + (size_t)CB * 38400);
  float* outf = (float*)d_out;

  prep_kernel<<<2659, 256, 0, stream>>>(
      wq, wk, wv, wo, wqf, lnqg, lnqb, lnkg, lnkb, lnvg, lnvb,
      relt, gbias, alph, wqp, bqp, bqf, bo,
      wT, woT, wqfT, params);
  xconv_kernel<<<12800, 256, 0, stream>>>(x, x_bf);

  for (int c = 0; c < nchunks; ++c) {
    const long long R0 = (long long)c * rows;

    // conv q/k/v projection + fused LN + residual (XCD-aware 1-D grid)
    convln_kernel<<<3 * (rows / 64), 256, 0, stream>>>(
        x_bf, R0, wT, qkv_c, params, zpad);

    // qf: [rows x 64] = x @ wqf + bqf
    gemm_kernel<64, true, false, false><<<dim3(1, rows / 128), 256, 0, stream>>>(
        x_bf, 256, R0, wqfT, 256, qf_c, 64, params + 7456, 4, 1);

    // fused attention per batch
    attn_kernel<<<CB, 256, 0, stream>>>(qkv_c, qf_c, params);

    // output projection: [rows x 256] = attn_out @ wo + bo (f32 out, XCD-paired grid)
    gemm_kernel<128, true, true, true><<<2 * (rows / 128), 256, 0, stream>>>(
        qkv_c, 768, 0, woT, 256, outf + (size_t)R0 * 256, 256, params + 7520, 4, 2);
  }
}

// Round 22
// 361.056 us; speedup vs baseline: 1.9843x; 1.0267x over previous
//
#include <hip/hip_runtime.h>
#include <hip/hip_bf16.h>
#include <stdint.h>

using u16 = unsigned short;
using u32 = unsigned int;

typedef __attribute__((ext_vector_type(8))) __bf16 bf16x8;
typedef __attribute__((ext_vector_type(4))) float f32x4;

// ---------- helpers ----------
__device__ __forceinline__ float bf2f(u16 h) {
  u32 u = ((u32)h) << 16;
  return __builtin_bit_cast(float, u);
}
__device__ __forceinline__ u16 f2bf(float f) {
  u32 u = __builtin_bit_cast(u32, f);
  u += 0x7fffu + ((u >> 16) & 1u);   // RNE
  return (u16)(u >> 16);
}
__device__ __forceinline__ float blo(u32 u) { return __builtin_bit_cast(float, u << 16); }
__device__ __forceinline__ float bhi(u32 u) { return __builtin_bit_cast(float, u & 0xffff0000u); }

__device__ __forceinline__ uint4 cvt8(const float* s) {
  float4 f0 = *(const float4*)s;
  float4 f1 = *(const float4*)(s + 4);
  uint4 r;
  r.x = (u32)f2bf(f0.x) | ((u32)f2bf(f0.y) << 16);
  r.y = (u32)f2bf(f0.z) | ((u32)f2bf(f0.w) << 16);
  r.z = (u32)f2bf(f1.x) | ((u32)f2bf(f1.y) << 16);
  r.w = (u32)f2bf(f1.z) | ((u32)f2bf(f1.w) << 16);
  return r;
}

// tanh of packed bf16 differences
__device__ __forceinline__ u32 tanh2(u32 a, u32 b) {
  const float d0 = blo(a) - blo(b);
  const float d1 = bhi(a) - bhi(b);
  const float e0 = __expf(2.f * d0), e1 = __expf(2.f * d1);
  const float t0 = 1.f - 2.f * __builtin_amdgcn_rcpf(e0 + 1.f);
  const float t1 = 1.f - 2.f * __builtin_amdgcn_rcpf(e1 + 1.f);
  return (u32)f2bf(t0) | ((u32)f2bf(t1) << 16);
}

__device__ __forceinline__ void gl_lds(const u16* gsrc, u16* ldsbase) {
  __builtin_amdgcn_global_load_lds(
      (const __attribute__((address_space(1))) u32*)gsrc,
      (__attribute__((address_space(3))) u32*)ldsbase, 16, 0, 0);
}

// ---------- ws layout (bytes) ----------
//  params @ 0 (8864 u16 = 17728, pad 32768) | wT @ 32768 (1,179,648)
//  woT @ 1,212,416 (131,072) | wqfT @ 1,343,488 (32,768)  -> fixed = 1,376,256
//  x_bf @ fixed (52,428,800) | chunk after: qkv CB*38400, qf CB*3200
// params (u16): LN 0(1536) REL 1536(392) GBC 1928(5000 = rel+alpha*gbias+bqp)
//  ALPHA 6928(8) WQP 6936(512) BQP 7448(8) BQF 7456(64) BO 7520(256)
//  WQPT16 7776(1024 = [16 cols][64 k], cols 8-15 zero) ZPAD 8800(64 zeros)

// ---------- prep ----------
__global__ __launch_bounds__(256) void prep_kernel(
    const float* __restrict__ wq, const float* __restrict__ wk, const float* __restrict__ wv,
    const float* __restrict__ wo, const float* __restrict__ wqf,
    const float* __restrict__ lnqg, const float* __restrict__ lnqb,
    const float* __restrict__ lnkg, const float* __restrict__ lnkb,
    const float* __restrict__ lnvg, const float* __restrict__ lnvb,
    const float* __restrict__ relt, const float* __restrict__ gbias,
    const float* __restrict__ alphap,
    const float* __restrict__ wqp, const float* __restrict__ bqp,
    const float* __restrict__ bqf, const float* __restrict__ bo,
    u16* __restrict__ wT, u16* __restrict__ woT,
    u16* __restrict__ wqfT, u16* __restrict__ params)
{
  long long j = (long long)blockIdx.x * 256 + threadIdx.x;
  if (j < 589824) {                 // wT[col][k] = w_p[o][i][t], k=t*256+i
    int col = (int)(j / 768), k = (int)(j % 768);
    int p = col >> 8, o = col & 255, t = k >> 8, i = k & 255;
    const float* w = (p == 0) ? wq : (p == 1) ? wk : wv;
    wT[j] = f2bf(w[o * 768 + i * 3 + t]);
    return;
  }
  j -= 589824;
  if (j < 65536) {                  // woT[n][k] = wo[k][n]
    int n = (int)(j >> 8), k = (int)(j & 255);
    woT[j] = f2bf(wo[k * 256 + n]);
    return;
  }
  j -= 65536;
  if (j < 16384) {                  // wqfT[col][k] = wqf[k][col]
    int col = (int)(j >> 8), k = (int)(j & 255);
    wqfT[j] = f2bf(wqf[k * 64 + col]);
    return;
  }
  j -= 16384;
  if (j < 8864) {
    int t = (int)j;
    if (t >= 8800) { params[t] = 0; return; }               // zpad
    if (t >= 7776) {                                        // wqpT16[col][k]
      int t2 = t - 7776;
      int col = t2 >> 6, k = t2 & 63;
      params[t] = (col < 8) ? f2bf(wqp[k * 8 + col]) : (u16)0;
      return;
    }
    if (t >= 1928 && t < 6928) {    // combined bias: rel + alpha*gbias + bqp
      int idx = t - 1928;
      int h = idx / 625, rem = idx % 625, n = rem / 25, m = rem % 25;
      params[t] = f2bf(gbias[idx] * alphap[0] + relt[(n - m + 24) * 8 + h] + bqp[h]);
      return;
    }
    const float* src; int si;
    if (t < 1536) {
      int a = t >> 8, c = t & 255;
      src = (a == 0) ? lnqg : (a == 1) ? lnqb : (a == 2) ? lnkg
          : (a == 3) ? lnkb : (a == 4) ? lnvg : lnvb;
      si = c;
    } else if (t < 1928) { src = relt;  si = t - 1536; }
    else if (t < 6936)   { src = alphap; si = 0; }
    else if (t < 7448)   { src = wqp;   si = t - 6936; }
    else if (t < 7456)   { src = bqp;   si = t - 7448; }
    else if (t < 7520)   { src = bqf;   si = t - 7456; }
    else                 { src = bo;    si = t - 7520; }
    params[t] = f2bf(src[si]);
  }
}

// ---------- xconv: x (f32) -> x_bf ----------
__global__ __launch_bounds__(256) void xconv_kernel(
    const float* __restrict__ x, u16* __restrict__ xbf)
{
  const long long i = ((long long)blockIdx.x * 256 + threadIdx.x) * 8;
  *(uint4*)&xbf[i] = cvt8(x + i);
}

// ---------- convln: conv GEMM (BM=64 x BN=256) + fused LN + residual + qf tail blocks ----
// 256 threads = 4 waves. Grid = 4*ny blocks:
//  [0, 3*ny):   conv projections, XCD-aware decode (3 projections of same y-tile -> same XCD)
//  [3*ny, 4*ny): qf tile blocks (64 rows x 64 cols, 4 K-steps, light path)
__global__ __launch_bounds__(256) void convln_kernel(
    const u16* __restrict__ xbf, long long row0,
    const u16* __restrict__ wT, const u16* __restrict__ wqfT,
    u16* __restrict__ C,                 // chunk-local qkv [rows][768]
    u16* __restrict__ qfc,               // chunk-local qf [rows][64]
    const u16* __restrict__ params,
    const u16* __restrict__ zpad,
    int ny)
{
  __shared__ __align__(16) u16 Asm[64 * 64];
  __shared__ __align__(16) u16 Bsm[256 * 64];
  __shared__ float sG[256];
  __shared__ float sB[256];
  __shared__ float sSum[4][64];
  __shared__ float sSq[4][64];

  const int tid = threadIdx.x;
  const int l = tid & 63, w = tid >> 6;
  const int lrow = l >> 3, chunk = l & 7;
  const int l15 = l & 15;
  const int rbase = 4 * (l >> 4);
  const int swz = l15 & 7;                // read-side chunk XOR (== row&7 for frag rows)

  if ((int)blockIdx.x < 3 * ny) {
    // ---------------- conv projection path ----------------
    const int ny8 = ny & ~7;
    int p, y;
    if ((int)blockIdx.x < 3 * ny8) {
      const int g = blockIdx.x / 24, r2 = blockIdx.x % 24;
      p = r2 >> 3;
      y = g * 8 + (r2 & 7);
    } else {
      const int b2 = blockIdx.x - 3 * ny8;
      const int nt = ny - ny8;
      p = b2 / nt;
      y = ny8 + b2 % nt;
    }
    const int c0 = p * 256;
    const int r0 = y * 64;

    sG[tid] = bf2f(params[p * 512 + tid]);
    sB[tid] = bf2f(params[p * 512 + 256 + tid]);

    f32x4 acc[4][4];
#pragma unroll
    for (int m = 0; m < 4; ++m)
#pragma unroll
      for (int n = 0; n < 4; ++n)
        acc[m][n] = (f32x4){0.f, 0.f, 0.f, 0.f};

    for (int ks = 0; ks < 12; ++ks) {
      const int k0 = ks * 64;
      const int t = k0 >> 8, kc = k0 & 255;
      __syncthreads();
      // stage A (64x64): 8 segs, 2/wave; source pre-swizzled by chunk^lrow
#pragma unroll
      for (int it = 0; it < 2; ++it) {
        const int seg = w * 2 + it;
        const int row_l = seg * 8 + lrow;
        const bool valid = ((unsigned)((r0 + row_l) % 25 + t - 1) < 25u);
        const u16* src = valid
            ? xbf + (size_t)(row0 + r0 + row_l + t - 1) * 256 + kc + ((chunk ^ lrow) << 3)
            : zpad;
        gl_lds(src, &Asm[seg * 512]);
      }
      // stage B (256x64): 32 segs, 8/wave
#pragma unroll
      for (int it = 0; it < 8; ++it) {
        const int seg = w * 8 + it;
        const int row_l = seg * 8 + lrow;
        const u16* src = wT + (size_t)(c0 + row_l) * 768 + k0 + ((chunk ^ lrow) << 3);
        gl_lds(src, &Bsm[seg * 512]);
      }
      __syncthreads();

#pragma unroll
      for (int kk = 0; kk < 64; kk += 32) {
        const int c = (kk >> 3) + (l >> 4);
        const int co = ((c ^ swz) << 3);
        bf16x8 av[4], bv[4];
#pragma unroll
        for (int m = 0; m < 4; ++m)
          av[m] = *(const bf16x8*)&Asm[(m * 16 + l15) * 64 + co];
#pragma unroll
        for (int n = 0; n < 4; ++n)
          bv[n] = *(const bf16x8*)&Bsm[(w * 64 + n * 16 + l15) * 64 + co];
#pragma unroll
        for (int m = 0; m < 4; ++m)
#pragma unroll
          for (int n = 0; n < 4; ++n)
            acc[m][n] = __builtin_amdgcn_mfma_f32_16x16x32_bf16(av[m], bv[n], acc[m][n], 0, 0, 0);
      }
    }

    // ---- LN stats: per-thread partials -> 4 shuffles -> cross-wave LDS combine
#pragma unroll
    for (int m = 0; m < 4; ++m) {
#pragma unroll
      for (int r = 0; r < 4; ++r) {
        float s = 0.f, q = 0.f;
#pragma unroll
        for (int n = 0; n < 4; ++n) { const float v = acc[m][n][r]; s += v; q += v * v; }
#pragma unroll
        for (int mk = 1; mk < 16; mk <<= 1) {
          s += __shfl_xor(s, mk, 64);
          q += __shfl_xor(q, mk, 64);
        }
        if (l15 == 0) {
          const int row = m * 16 + rbase + r;
          sSum[w][row] = s;
          sSq[w][row] = q;
        }
      }
    }
    __syncthreads();

    // ---- normalize + gamma/beta + residual, store
#pragma unroll
    for (int m = 0; m < 4; ++m) {
      float mu4[4], rs4[4];
#pragma unroll
      for (int r = 0; r < 4; ++r) {
        const int row = m * 16 + rbase + r;
        const float tot = sSum[0][row] + sSum[1][row] + sSum[2][row] + sSum[3][row];
        const float tq  = sSq[0][row] + sSq[1][row] + sSq[2][row] + sSq[3][row];
        const float mu = tot * (1.f / 256.f);
        const float var = tq * (1.f / 256.f) - mu * mu;
        mu4[r] = mu;
        rs4[r] = rsqrtf(var + 1e-5f);
      }
#pragma unroll
      for (int n = 0; n < 4; ++n) {
        const int lc = w * 64 + n * 16 + l15;
        const float g = sG[lc], bb = sB[lc];
#pragma unroll
        for (int r = 0; r < 4; ++r) {
          const int row = m * 16 + rbase + r;
          const float xv = bf2f(xbf[(size_t)(row0 + r0 + row) * 256 + lc]);
          const float v = (acc[m][n][r] - mu4[r]) * rs4[r] * g + bb + xv;
          C[(size_t)(r0 + row) * 768 + c0 + lc] = f2bf(v);
        }
      }
    }
  } else {
    // ---------------- qf tail path: [64 x 64] = x @ wqfT^T ----------------
    const int r0 = (blockIdx.x - 3 * ny) * 64;

    f32x4 acc2[4];
#pragma unroll
    for (int n = 0; n < 4; ++n) acc2[n] = (f32x4){0.f, 0.f, 0.f, 0.f};

    for (int ki = 0; ki < 4; ++ki) {
      __syncthreads();
      // stage A (64x64): plain x rows, 8 segs, 2/wave
#pragma unroll
      for (int it = 0; it < 2; ++it) {
        const int seg = w * 2 + it;
        const int row_l = seg * 8 + lrow;
        const u16* src = xbf + (size_t)(row0 + r0 + row_l) * 256 + ki * 64
                       + ((chunk ^ lrow) << 3);
        gl_lds(src, &Asm[seg * 512]);
      }
      // stage B (64x64): wqfT rows, 8 segs, 2/wave
#pragma unroll
      for (int it = 0; it < 2; ++it) {
        const int seg = w * 2 + it;
        const int row_l = seg * 8 + lrow;
        const u16* src = wqfT + (size_t)row_l * 256 + ki * 64 + ((chunk ^ lrow) << 3);
        gl_lds(src, &Bsm[seg * 512]);
      }
      __syncthreads();

#pragma unroll
      for (int kk = 0; kk < 64; kk += 32) {
        const int c = (kk >> 3) + (l >> 4);
        const int co = ((c ^ swz) << 3);
        const bf16x8 av = *(const bf16x8*)&Asm[(w * 16 + l15) * 64 + co];
#pragma unroll
        for (int n = 0; n < 4; ++n) {
          const bf16x8 bv = *(const bf16x8*)&Bsm[(n * 16 + l15) * 64 + co];
          acc2[n] = __builtin_amdgcn_mfma_f32_16x16x32_bf16(av, bv, acc2[n], 0, 0, 0);
        }
      }
    }
#pragma unroll
    for (int n = 0; n < 4; ++n) {
      const int col = n * 16 + l15;
      const float badd = bf2f(params[7456 + col]);
#pragma unroll
      for (int r = 0; r < 4; ++r) {
        const int row = r0 + w * 16 + rbase + r;
        qfc[(size_t)row * 64 + col] = f2bf(acc2[n][r] + badd);
      }
    }
  }
}

// ---------- MFMA GEMM (bf16 A, global_load_lds, XOR-swizzled): tiles 128 x BN ----------
// XCDP: 1-D grid, col-tiles of the same y-row-panel co-located on one XCD.
template<int BN, bool HAS_BIAS, bool F32OUT, bool XCDP>
__global__ __launch_bounds__(256) void gemm_kernel(
    const u16* __restrict__ A, int lda, long long row0,
    const u16* __restrict__ BT, int ldb,
    void* __restrict__ Cv, int ldc,
    const u16* __restrict__ bias,
    int ksteps, int ncols)
{
  constexpr int NB = BN / 32;
  __shared__ __align__(16) u16 Asm[128 * 64];
  __shared__ __align__(16) u16 Bsm[BN * 64];

  const int tid = threadIdx.x;
  const int l = tid & 63;
  const int w = tid >> 6;

  int c0, r0;
  if constexpr (XCDP) {
    const int ny = gridDim.x / ncols;
    const int ny8 = ny & ~7;
    const int grp = ncols * 8;
    int cx, y;
    if ((int)blockIdx.x < ncols * ny8) {
      const int g = blockIdx.x / grp, r2 = blockIdx.x % grp;
      cx = r2 >> 3;
      y = g * 8 + (r2 & 7);
    } else {
      const int b2 = blockIdx.x - ncols * ny8;
      const int nt = ny - ny8;
      cx = b2 / nt;
      y = ny8 + b2 % nt;
    }
    c0 = cx * BN;
    r0 = y * 128;
  } else {
    c0 = blockIdx.x * BN;
    r0 = blockIdx.y * 128;
  }
  const int wr = w >> 1, wc = w & 1;

  f32x4 acc[4][NB];
#pragma unroll
  for (int m = 0; m < 4; ++m)
#pragma unroll
    for (int n = 0; n < NB; ++n)
      acc[m][n] = (f32x4){0.f, 0.f, 0.f, 0.f};

  const int lrow = l >> 3;
  const int chunk = l & 7;
  const int l15 = l & 15;
  const int swz = l15 & 7;

  for (int ks = 0; ks < ksteps; ++ks) {
    const int k0 = ks * 64;
    __syncthreads();
#pragma unroll
    for (int it = 0; it < 4; ++it) {
      const int seg = w * 4 + it;
      const int row_l = seg * 8 + lrow;
      const u16* src = A + (size_t)(row0 + r0 + row_l) * lda + k0 + ((chunk ^ lrow) << 3);
      gl_lds(src, &Asm[seg * 512]);
    }
#pragma unroll
    for (int it = 0; it < NB; ++it) {
      const int seg = w * NB + it;
      const int row_l = seg * 8 + lrow;
      const u16* src = BT + (size_t)(c0 + row_l) * ldb + k0 + ((chunk ^ lrow) << 3);
      gl_lds(src, &Bsm[seg * 512]);
    }
    __syncthreads();

#pragma unroll
    for (int kk = 0; kk < 64; kk += 32) {
      const int c = (kk >> 3) + (l >> 4);
      const int co = ((c ^ swz) << 3);
      bf16x8 av[4], bv[NB];
#pragma unroll
      for (int m = 0; m < 4; ++m)
        av[m] = *(const bf16x8*)&Asm[(wr * 64 + m * 16 + l15) * 64 + co];
#pragma unroll
      for (int n = 0; n < NB; ++n)
        bv[n] = *(const bf16x8*)&Bsm[(wc * (BN / 2) + n * 16 + l15) * 64 + co];
#pragma unroll
      for (int m = 0; m < 4; ++m)
#pragma unroll
        for (int n = 0; n < NB; ++n)
          acc[m][n] = __builtin_amdgcn_mfma_f32_16x16x32_bf16(av[m], bv[n], acc[m][n], 0, 0, 0);
    }
  }

  const int rbase = 4 * (l >> 4);
#pragma unroll
  for (int m = 0; m < 4; ++m) {
#pragma unroll
    for (int n = 0; n < NB; ++n) {
      const int col = c0 + wc * (BN / 2) + n * 16 + l15;
      float badd = 0.f;
      if (HAS_BIAS) badd = bf2f(bias[col]);
#pragma unroll
      for (int r = 0; r < 4; ++r) {
        const int row = r0 + wr * 64 + m * 16 + rbase + r;
        const float v = acc[m][n][r] + badd;
        if constexpr (F32OUT) ((float*)Cv)[(size_t)row * ldc + col] = v;
        else                  ((u16*)Cv)[(size_t)row * ldc + col] = f2bf(v);
      }
    }
  }
}

// ---------- fused attention per batch (LN already applied to qkv) ----------
// LDS 38,848 B -> 4 blocks/CU, 4 barriers
__global__ __launch_bounds__(256) void attn_kernel(
    u16* __restrict__ qkv,                  // chunk-local [CB*25][768]; cols 0-255 get attn_out
    const u16* __restrict__ qf,             // chunk-local [CB*25][64]
    const u16* __restrict__ params)
{
  __shared__ __align__(16) char arena[38848];
  float* sS    = (float*)arena;
  u16*   sV    = (u16*)(arena + 20000);
  u16*   sQF   = (u16*)(arena + 33200);
  u16*   sWQPT = (u16*)(arena + 36800);

  const int b = blockIdx.x;
  const int tid = threadIdx.x;
  const int w = tid >> 6, l = tid & 63;
  const int g8 = (l >> 4) * 8;
  const int rbase = 4 * (l >> 4);
  const int l15 = l & 15;

  // ---- P0: stage V (LN'd), qf, wqpT
  {
    for (int i = tid; i < 800; i += 256) {
      const int m = i >> 5, c8 = (i & 31) * 8;
      *(uint4*)&sV[m * 264 + c8] =
          *(const uint4*)(qkv + (size_t)(b * 25 + m) * 768 + 512 + c8);
    }
    for (int i = tid; i < 200; i += 256) {
      const int r = i >> 3, c8 = (i & 7) * 8;
      *(uint4*)&sQF[r * 72 + c8] = *(const uint4*)(qf + (size_t)b * 1600 + r * 64 + c8);
    }
    for (int i = tid; i < 128; i += 256)
      ((uint4*)sWQPT)[i] = ((const uint4*)(params + 7776))[i];
  }
  __syncthreads();

  // ---- P1: dyn-bias tiles in registers + scores via MFMA (Q/K direct from global)
  f32x4 dt[10];
  {
    const bf16x8 bv0 = *(const bf16x8*)&sWQPT[l15 * 64 + g8];
    const bf16x8 bv1 = *(const bf16x8*)&sWQPT[l15 * 64 + 32 + g8];
#pragma unroll
    for (int ti = 0; ti < 10; ++ti) {
      const int p0 = (ti * 4 + w) * 16;
      int p = p0 + l15; if (p > 624) p = 624;
      const int n = p / 25, m = p % 25;
      const uint4 qn0 = *(const uint4*)&sQF[n * 72 + g8];
      const uint4 qn1 = *(const uint4*)&sQF[n * 72 + 32 + g8];
      const uint4 qm0 = *(const uint4*)&sQF[m * 72 + g8];
      const uint4 qm1 = *(const uint4*)&sQF[m * 72 + 32 + g8];
      u32 a0[4], a1[4];
      a0[0] = tanh2(qn0.x, qm0.x); a0[1] = tanh2(qn0.y, qm0.y);
      a0[2] = tanh2(qn0.z, qm0.z); a0[3] = tanh2(qn0.w, qm0.w);
      a1[0] = tanh2(qn1.x, qm1.x); a1[1] = tanh2(qn1.y, qm1.y);
      a1[2] = tanh2(qn1.z, qm1.z); a1[3] = tanh2(qn1.w, qm1.w);
      const bf16x8 av0 = __builtin_bit_cast(bf16x8, *(uint4*)a0);
      const bf16x8 av1 = __builtin_bit_cast(bf16x8, *(uint4*)a1);
      f32x4 d = (f32x4){0.f, 0.f, 0.f, 0.f};
      d = __builtin_amdgcn_mfma_f32_16x16x32_bf16(av0, bv0, d, 0, 0, 0);
      d = __builtin_amdgcn_mfma_f32_16x16x32_bf16(av1, bv1, d, 0, 0, 0);
      dt[ti] = d;
    }
    // scores: 2 heads/wave; fragments straight from global (16 rows x 64B pattern)
    bf16x8 zf8;
#pragma unroll
    for (int j = 0; j < 8; ++j) zf8[j] = (__bf16)0.f;
#pragma unroll
    for (int hh = 0; hh < 2; ++hh) {
      const int h = 2 * w + hh;
      bf16x8 qa[2], kb[2];
#pragma unroll
      for (int t = 0; t < 2; ++t) {
        const int row = l15 + 16 * t;
        if (row < 25) {
          const u16* base = qkv + (size_t)(b * 25 + row) * 768 + h * 32 + g8;
          qa[t] = *(const bf16x8*)base;
          kb[t] = *(const bf16x8*)(base + 256);
        } else { qa[t] = zf8; kb[t] = zf8; }
      }
#pragma unroll
      for (int tn = 0; tn < 2; ++tn)
#pragma unroll
        for (int tm = 0; tm < 2; ++tm) {
          f32x4 d = __builtin_amdgcn_mfma_f32_16x16x32_bf16(
              qa[tn], kb[tm], (f32x4){0.f, 0.f, 0.f, 0.f}, 0, 0, 0);
          const int m = l15 + 16 * tm;
#pragma unroll
          for (int r = 0; r < 4; ++r) {
            const int n = rbase + r + 16 * tn;
            if (n < 25 && m < 25) {
              const int idx = h * 625 + n * 25 + m;
              sS[idx] = d[r] * 0.17677669529663687f + bf2f(params[1928 + idx]);
            }
          }
        }
    }
  }
  __syncthreads();

  // ---- P2: scatter-add dyn tiles into sS
  {
    if (l15 < 8) {
      const int h = l15;
#pragma unroll
      for (int ti = 0; ti < 10; ++ti) {
        const int p0 = (ti * 4 + w) * 16;
#pragma unroll
        for (int r = 0; r < 4; ++r) {
          const int p = p0 + rbase + r;
          if (p < 625) sS[h * 625 + p] += dt[ti][r];
        }
      }
    }
  }
  __syncthreads();

  // ---- P3: softmax over m
  {
    for (int u = tid; u < 200; u += 256) {
      const int h = u / 25, n = u % 25;
      float* rp = &sS[h * 625 + n * 25];
      float mx = -1e30f;
#pragma unroll
      for (int m = 0; m < 25; ++m) mx = fmaxf(mx, rp[m]);
      float ssum = 0.f;
#pragma unroll
      for (int m = 0; m < 25; ++m) { rp[m] = __expf(rp[m] - mx); ssum += rp[m]; }
      const float inv = __builtin_amdgcn_rcpf(ssum);
#pragma unroll
      for (int m = 0; m < 25; ++m) rp[m] *= inv;
    }
  }
  __syncthreads();

  // ---- P4: PV via MFMA -> global qkv cols 0-255
  {
#pragma unroll
    for (int hh = 0; hh < 2; ++hh) {
      const int h = 2 * w + hh;
      bf16x8 pa[2], vb[2];
#pragma unroll
      for (int t = 0; t < 2; ++t) {
        const int n = l15 + 16 * t;
#pragma unroll
        for (int j = 0; j < 8; ++j) {
          const int m = g8 + j;
          const float pv = (n < 25 && m < 25) ? sS[h * 625 + n * 25 + m] : 0.f;
          pa[t][j] = (__bf16)pv;
        }
      }
#pragma unroll
      for (int t = 0; t < 2; ++t) {
        const int dcol = l15 + 16 * t;
#pragma unroll
        for (int j = 0; j < 8; ++j) {
          const int m = g8 + j;
          vb[t][j] = (m < 25)
              ? __builtin_bit_cast(__bf16, sV[m * 264 + h * 32 + dcol])
              : (__bf16)0.f;
        }
      }
#pragma unroll
      for (int tn = 0; tn < 2; ++tn)
#pragma unroll
        for (int td = 0; td < 2; ++td) {
          f32x4 d = __builtin_amdgcn_mfma_f32_16x16x32_bf16(
              pa[tn], vb[td], (f32x4){0.f, 0.f, 0.f, 0.f}, 0, 0, 0);
          const int dcol = l15 + 16 * td;
#pragma unroll
          for (int r = 0; r < 4; ++r) {
            const int n = rbase + r + 16 * tn;
            if (n < 25)
              qkv[(size_t)(b * 25 + n) * 768 + h * 32 + dcol] = f2bf(d[r]);
          }
        }
    }
  }
}

// ---------- launch ----------
extern "C" void kernel_launch(void* const* d_in, const int* in_sizes, int n_in,
                              void* d_out, int out_size, void* d_ws, size_t ws_size,
                              hipStream_t stream) {
  (void)in_sizes; (void)n_in; (void)out_size;
  const float* x    = (const float*)d_in[0];
  const float* wq   = (const float*)d_in[1];
  const float* wk   = (const float*)d_in[2];
  const float* wv   = (const float*)d_in[3];
  const float* lnqg = (const float*)d_in[4];
  const float* lnqb = (const float*)d_in[5];
  const float* lnkg = (const float*)d_in[6];
  const float* lnkb = (const float*)d_in[7];
  const float* lnvg = (const float*)d_in[8];
  const float* lnvb = (const float*)d_in[9];
  const float* relt = (const float*)d_in[10];
  const float* gbias= (const float*)d_in[11];
  const float* alph = (const float*)d_in[12];
  const float* wqf  = (const float*)d_in[13];
  const float* bqf  = (const float*)d_in[14];
  const float* wqp  = (const float*)d_in[15];
  const float* bqp  = (const float*)d_in[16];
  const float* wo   = (const float*)d_in[17];
  const float* bo   = (const float*)d_in[18];

  char* ws = (char*)d_ws;
  u16* params = (u16*)(ws + 0);
  u16* wT     = (u16*)(ws + 32768);
  u16* woT    = (u16*)(ws + 1212416);
  u16* wqfT   = (u16*)(ws + 1343488);
  const size_t fixed_bytes = 1376256;
  const size_t xbf_bytes = 52428800;
  const size_t per_batch = 41600;   // qkv 38400 + qf 3200 bytes
  u16* zpad = params + 8800;

  int CB = 4096;
  while (CB > 128 && fixed_bytes + xbf_bytes + (size_t)CB * per_batch > ws_size) CB >>= 1;
  const int nchunks = 4096 / CB;
  const int rows = CB * 25;

  u16* x_bf = (u16*)(ws + fixed_bytes);
  const size_t chunk_off = fixed_bytes + xbf_bytes;
  u16* qkv_c = (u16*)(ws + chunk_off);
  u16* qf_c  = (u16*)(ws + chunk_off + (size_t)CB * 38400);
  float* outf = (float*)d_out;

  prep_kernel<<<2659, 256, 0, stream>>>(
      wq, wk, wv, wo, wqf, lnqg, lnqb, lnkg, lnkb, lnvg, lnvb,
      relt, gbias, alph, wqp, bqp, bqf, bo,
      wT, woT, wqfT, params);
  xconv_kernel<<<12800, 256, 0, stream>>>(x, x_bf);

  for (int c = 0; c < nchunks; ++c) {
    const long long R0 = (long long)c * rows;
    const int ny = rows / 64;

    // conv q/k/v projection + fused LN + residual (XCD-aware) + qf tail blocks
    convln_kernel<<<4 * ny, 256, 0, stream>>>(
        x_bf, R0, wT, wqfT, qkv_c, qf_c, params, zpad, ny);

    // fused attention per batch
    attn_kernel<<<CB, 256, 0, stream>>>(qkv_c, qf_c, params);

    // output projection: [rows x 256] = attn_out @ wo + bo (f32 out, XCD-paired grid)
    gemm_kernel<128, true, true, true><<<2 * (rows / 128), 256, 0, stream>>>(
        qkv_c, 768, 0, woT, 256, outf + (size_t)R0 * 256, 256, params + 7520, 4, 2);
  }
}